// Round 10
// baseline (323.722 us; speedup 1.0000x reference)
//
#include <hip/hip_runtime.h>
#include <math.h>

#define L_TOT 36864
#define BN_EPS 1e-5f
#define PCH 45000   // padded channel stride: 18*50*50

typedef __attribute__((ext_vector_type(8))) short bf16x8;
typedef __attribute__((ext_vector_type(4))) float f32x4;

__device__ __forceinline__ float fsigmoid(float x){ return 1.f/(1.f+__expf(-x)); }
__device__ __forceinline__ float fsoftplus(float x){
  float e = __expf(x);
  return (x>20.f)? x : __logf(1.f+e);
}
__device__ __forceinline__ unsigned short f2bf(float x){
  union { float f; unsigned u; } cv; cv.f = x;
  unsigned r = (cv.u + 0x7FFFu + ((cv.u>>16)&1u)) >> 16;
  return (unsigned short)r;
}
__host__ __device__ constexpr int off3c(int r){
  return (r>=27) ? 0 : ((r/9)-1)*2500 + (((r%9)/3)-1)*50 + ((r%3)-1);
}

// =================================================================================
// k_front: fused LN (+BN-on-read) + in-proj + causal dwconv/SiLU + x-proj + dt +
//          pass1 chunk aggregates.  One block = one chunk of 24 timesteps.
// 1536 blocks = 6 blocks/CU (24 waves/CU ceiling, 2x the TCH=48 version).
// Lane layout: col i = tid&31 (24 cols + 3 halo used), row-group rw = tid>>5.
// Region0 (DI*32 floats) time-aliased: x/xn -> xs(+halo) -> dt(stride 25).
// SETUP=true (stage 1): folds weight pack / bfin halo zero / stats zero.
// =================================================================================
template<int DIM, int DI, int DTR, bool DOBN, bool SETUP>
__global__ __launch_bounds__(256,6) void k_front(
    const float* __restrict__ x0, const float* __restrict__ x1,
    const float* __restrict__ bstats, const float* __restrict__ bg, const float* __restrict__ bbp,
    const float* __restrict__ lnw, const float* __restrict__ lnb,
    const float* __restrict__ inw,
    const float* __restrict__ cw, const float* __restrict__ cb,
    const float* __restrict__ xpw,
    const float* __restrict__ dtw, const float* __restrict__ dtb,
    const float* __restrict__ Alog,
    float* __restrict__ xcg, float* __restrict__ zg,
    float* __restrict__ dtpg, float* __restrict__ Bg, float* __restrict__ Cg,
    float* __restrict__ aggA, float* __restrict__ aggB,
    const float* __restrict__ cvw1, unsigned short* __restrict__ wA1,
    const float* __restrict__ cvw2, unsigned short* __restrict__ wA2,
    float* __restrict__ stats, float* __restrict__ bfz)
{
  constexpr int TCH  = 24;
  constexpr int COLS = 32;
  constexpr int ROWS = DTR + 32;
  constexpr int NSH  = 256/DI;        // threads per d-channel in scan
  constexpr int SPB  = 16/NSH;        // states per thread
  constexpr int CH   = DI*16;
  constexpr int R0SZ = DI*COLS;       // region0: x/xn (DIM*32) / xs+halo (DI*32) / dt (stride25)
  constexpr int O_SXC = R0SZ;         // DI*25 (+8 pad, reads up to col 31)
  constexpr int O_SB  = O_SXC + DI*25 + 8;   // 16*25
  constexpr int O_SC  = O_SB + 16*25;        // 16*25
  constexpr int O_DTP = O_SC + 16*25;        // DTR*24
  constexpr int SMEM  = O_DTP + DTR*TCH + 16;
  __shared__ float sm[SMEM];

  const int tid   = threadIdx.x;
  const int chunk = blockIdx.x;
  const int t0    = chunk*TCH;

  // ---- folded setup (stage 1): outputs consumed only by later kernels ----------
  if constexpr (SETUP){
    for (int idx = blockIdx.x*256 + tid; idx < 16*PCH; idx += 1536*256)
      bfz[idx] = 0.f;                          // zero bf16 halo buffer (32-bit words)
    const int b = blockIdx.x;
    if (b < 4){
      int k = b*256 + tid;
      if (k < 864){
        int ic = k & 31, r = k >> 5;
        for (int m=0;m<16;m++){
          float v = (r < 27) ? cvw1[m*32*27 + ic*27 + r] : 0.f;
          wA1[(((k>>3)*16) + m)*8 + (k&7)] = f2bf(v);
        }
      }
    } else if (b < 6){
      int k = (b-4)*256 + tid;
      if (k < 448){
        int ic = k & 15, r = k >> 4;
        for (int m=0;m<16;m++){
          float v = (r < 27) ? cvw2[m*16*27 + ic*27 + r] : 0.f;
          wA2[(((k>>3)*16) + m)*8 + (k&7)] = f2bf(v);
        }
      }
    } else if (b == 6){
      if (tid < 64) stats[tid] = 0.f;
    }
  }

  // ---- P0: load x (+optional BN) into region0; cols 0..26 = t0-3 .. t0+23
  for (int idx = tid; idx < DIM*COLS; idx += 256){
    int c = idx >> 5, i2 = idx & 31;
    int t = t0 - 3 + i2;
    float v = 0.f;
    if (i2 < TCH+3 && t >= 0){
      if constexpr (DOBN){
        float raw = x0[c*L_TOT + t];
        float bm = bstats[2*c]*(1.f/L_TOT);
        float bv = bstats[2*c+1]*(1.f/L_TOT) - bm*bm;
        v = (raw - bm)*rsqrtf(bv+BN_EPS)*bg[c] + bbp[c];
      } else {
        v = (c < 16) ? x0[c*L_TOT + t] : x1[(c-16)*L_TOT + t];
      }
    }
    sm[idx] = v;
  }
  __syncthreads();

  // ---- P1: LayerNorm per column, in place (cols >=27 all-zero, stay finite)
  if (tid < 32){
    float s = 0.f, s2 = 0.f;
#pragma unroll
    for (int c = 0; c < DIM; c++){
      float v = sm[c*COLS + tid];
      s += v; s2 += v*v;
    }
    float m  = s*(1.f/DIM);
    float var = s2*(1.f/DIM) - m*m;
    float rs = rsqrtf(var + BN_EPS);
#pragma unroll
    for (int c = 0; c < DIM; c++){
      float v = sm[c*COLS + tid];
      sm[c*COLS + tid] = (v-m)*rs*lnw[c] + lnb[c];
    }
  }
  __syncthreads();

  // ---- P2: in-proj (row-serial).  xs rows -> region0 (over x), z rows -> global
  const int i  = tid & 31;
  const int rw = tid >> 5;           // 8 row-groups
  {
    float xn[DIM];
#pragma unroll
    for (int c = 0; c < DIM; c++) xn[c] = sm[c*COLS + i];
    __syncthreads();                 // everyone finished reading x; region0 reusable
    for (int r = rw; r < 2*DI; r += 8){
      float acc = 0.f;
#pragma unroll
      for (int c = 0; c < DIM; c++) acc += xn[c]*inw[r*DIM + c];
      if (r < DI){
        if (i < TCH+3) sm[r*COLS + i] = (t0 == 0 && i < 3) ? 0.f : acc;
      } else {
        if (i >= 3 && i < TCH+3) zg[(r-DI)*L_TOT + t0 + i - 3] = acc;
      }
    }
  }
  __syncthreads();

  // ---- P3: causal depthwise conv (kw=4) + SiLU -> SXC
  for (int idx = tid; idx < DI*TCH; idx += 256){
    int d = idx / TCH, j = idx - d*TCH;
    const float* xr = &sm[d*COLS + j];   // xr[k] = xs[t-3+k]
    float acc = cb[d] + cw[d*4+0]*xr[0] + cw[d*4+1]*xr[1]
                      + cw[d*4+2]*xr[2] + cw[d*4+3]*xr[3];
    sm[O_SXC + d*25 + j] = acc * fsigmoid(acc);
  }
  __syncthreads();

  // ---- P4: x-proj -> dtp | B | C
  {
    constexpr int NR = (ROWS + 7) / 8;
    float acc[NR];
#pragma unroll
    for (int rr = 0; rr < NR; rr++) acc[rr] = 0.f;
    for (int db = 0; db < DI; db += 16){
      float xcol[16];
#pragma unroll
      for (int k = 0; k < 16; k++) xcol[k] = sm[O_SXC + (db+k)*25 + i];
#pragma unroll
      for (int rr = 0; rr < NR; rr++){
        int r = rw + rr*8;
        if (r < ROWS){
          float a2 = 0.f;
#pragma unroll
          for (int k = 0; k < 16; k++) a2 += xcol[k]*xpw[r*DI + db + k];
          acc[rr] += a2;
        }
      }
    }
    if (i < TCH){
#pragma unroll
      for (int rr = 0; rr < NR; rr++){
        int r = rw + rr*8;
        if (r < ROWS){
          if (r < DTR)          sm[O_DTP + r*TCH + i] = acc[rr];
          else if (r < DTR+16)  sm[O_SB + (r-DTR)*25 + i] = acc[rr];
          else                  sm[O_SC + (r-DTR-16)*25 + i] = acc[rr];
        }
      }
    }
  }
  __syncthreads();

  // ---- P5: dt = softplus(dtb + dtw*dtp) -> region0 (xs dead), stride 25
  for (int idx = tid; idx < DI*TCH; idx += 256){
    int d = idx / TCH, j = idx - d*TCH;
    float pre = dtb[d] + dtw[d*DTR]*sm[O_DTP + j];
    if (DTR > 1) pre += dtw[d*DTR + DTR-1]*sm[O_DTP + (DTR-1)*TCH + j];
    sm[d*25 + j] = fsoftplus(pre);
  }
  __syncthreads();

  // ---- P6: spill xc/dtp/B/C to global, float4 (stores fly during pass1)
  for (int idx = tid; idx < DI*6; idx += 256){
    int d = idx / 6, q = idx - d*6;
    float4 v = make_float4(sm[O_SXC + d*25 + q*4+0], sm[O_SXC + d*25 + q*4+1],
                           sm[O_SXC + d*25 + q*4+2], sm[O_SXC + d*25 + q*4+3]);
    *reinterpret_cast<float4*>(xcg + d*L_TOT + t0 + q*4) = v;
  }
  for (int idx = tid; idx < ROWS*6; idx += 256){
    int r = idx / 6, q = idx - r*6;
    const float* src; float* dst;
    if (r < DTR)        { src = &sm[O_DTP + r*TCH + q*4];         dst = dtpg + r*L_TOT + t0 + q*4; }
    else if (r < DTR+16){ src = &sm[O_SB + (r-DTR)*25 + q*4];     dst = Bg + (r-DTR)*L_TOT + t0 + q*4; }
    else                { src = &sm[O_SC + (r-DTR-16)*25 + q*4];  dst = Cg + (r-DTR-16)*L_TOT + t0 + q*4; }
    *reinterpret_cast<float4*>(dst) = make_float4(src[0], src[1], src[2], src[3]);
  }

  // ---- P7: pass1 scan -> per-chunk (A,B) aggregates
  {
    const int d  = tid / NSH;
    const int sh = tid - d*NSH;
    float Av[SPB], Ar[SPB], Br[SPB];
#pragma unroll
    for (int j = 0; j < SPB; j++){
      Av[j] = -__expf(Alog[d*16 + sh*SPB + j]);
      Ar[j] = 1.f; Br[j] = 0.f;
    }
    for (int t = 0; t < TCH; t++){
      float dtv = sm[d*25 + t];
      float bb2 = dtv * sm[O_SXC + d*25 + t];
#pragma unroll
      for (int j = 0; j < SPB; j++){
        float a2 = __expf(dtv*Av[j]);
        Ar[j] *= a2;
        Br[j] = a2*Br[j] + bb2*sm[O_SB + (sh*SPB+j)*25 + t];
      }
    }
    const int o = chunk*CH + tid*SPB;
    if constexpr (SPB == 4){
      *reinterpret_cast<float4*>(&aggA[o]) = make_float4(Ar[0],Ar[1],Ar[2],Ar[3]);
      *reinterpret_cast<float4*>(&aggB[o]) = make_float4(Br[0],Br[1],Br[2],Br[3]);
    } else {
      *reinterpret_cast<float2*>(&aggA[o]) = make_float2(Ar[0],Ar[1]);
      *reinterpret_cast<float2*>(&aggB[o]) = make_float2(Br[0],Br[1]);
    }
  }
}

// ---------------- parallel scan over chunk aggregates -> carries ------------------
// 8 channels x 32 segments per 256-thread block; grid = CH/8 blocks.
// Serial depth per segment = 1536/32 = 48 (same as the TCH=48 version).
template<int NCH>
__global__ __launch_bounds__(256) void k_carry(const float* __restrict__ aggA,
                        const float* __restrict__ aggB,
                        float* __restrict__ carry, int CH) {
  constexpr int SEGS = 32, CHB = 8;
  constexpr int SLEN = NCH/SEGS;       // 48 chunks per segment
  const int chl = threadIdx.x & 7;
  const int seg = threadIdx.x >> 3;
  const int ch  = blockIdx.x*CHB + chl;
  const int c0  = seg*SLEN;
  float a = 1.f, b = 0.f;
  for (int cb=c0; cb<c0+SLEN; cb+=8){
    float av[8], bv[8];
#pragma unroll
    for (int k=0;k<8;k++){ av[k]=aggA[(cb+k)*CH+ch]; bv[k]=aggB[(cb+k)*CH+ch]; }
#pragma unroll
    for (int k=0;k<8;k++){ a = a*av[k]; b = av[k]*b + bv[k]; }
  }
  __shared__ float sa[SEGS][CHB+1], sb[SEGS][CHB+1];
  sa[seg][chl]=a; sb[seg][chl]=b;
  __syncthreads();
  if (threadIdx.x < CHB){
    float pa=1.f, pb=0.f;
    for (int g=0; g<SEGS; g++){
      float ca=sa[g][threadIdx.x], cb2=sb[g][threadIdx.x];
      sa[g][threadIdx.x]=pa; sb[g][threadIdx.x]=pb;
      float na = pa*ca;
      float nb = ca*pb + cb2;
      pa=na; pb=nb;
    }
  }
  __syncthreads();
  float h = sb[seg][chl];
  for (int cb=c0; cb<c0+SLEN; cb+=8){
    float av[8], bv[8];
#pragma unroll
    for (int k=0;k<8;k++){ av[k]=aggA[(cb+k)*CH+ch]; bv[k]=aggB[(cb+k)*CH+ch]; }
#pragma unroll
    for (int k=0;k<8;k++){ carry[(cb+k)*CH+ch]=h; h = av[k]*h + bv[k]; }
  }
}

// =================================================================================
// k_back: fused pass2 scan + z-gate + out-proj + residual -> bf16 padded layout.
// One block = one chunk of 24 timesteps; 1536 blocks = 6 blocks/CU.
// =================================================================================
template<int DIM, int DI, int DTR, int RES>
__global__ __launch_bounds__(256,6) void k_back(
    const float* __restrict__ xcg, const float* __restrict__ zg,
    const float* __restrict__ dtpg, const float* __restrict__ Bg, const float* __restrict__ Cg,
    const float* __restrict__ dtw, const float* __restrict__ dtb,
    const float* __restrict__ Alog, const float* __restrict__ Dp,
    const float* __restrict__ carry,
    const float* __restrict__ ow,
    const float* __restrict__ r0src, const float* __restrict__ r1src,
    const float* __restrict__ bstats, const float* __restrict__ bg, const float* __restrict__ bbp,
    unsigned short* __restrict__ rp)
{
  constexpr int TCH = 24;
  constexpr int NSH = 256/DI;
  constexpr int SPB = 16/NSH;
  constexpr int ROWS = DTR + 32;
  constexpr int O_SXC = 0;                       // DI*25 + 8
  constexpr int O_SDT = O_SXC + DI*25 + 8;       // DI*25 + 8
  constexpr int O_SB  = O_SDT + DI*25 + 8;       // 16*25
  constexpr int O_SC  = O_SB + 16*25;            // 16*25
  constexpr int O_SY  = O_SC + 16*25;            // DI*25 + 8
  constexpr int O_DTP = O_SY + DI*25 + 8;        // DTR*24
  constexpr int SMEM  = O_DTP + DTR*TCH + 16;
  __shared__ float sm[SMEM];
  const int tid   = threadIdx.x;
  const int chunk = blockIdx.x;
  const int t0    = chunk*TCH;

  // ---- load xc / B / C / dtp (float4 global, scalar LDS scatter)
  for (int idx = tid; idx < DI*6; idx += 256){
    int d = idx / 6, q = idx - d*6;
    float4 v = *reinterpret_cast<const float4*>(xcg + d*L_TOT + t0 + q*4);
    sm[O_SXC + d*25 + q*4+0] = v.x; sm[O_SXC + d*25 + q*4+1] = v.y;
    sm[O_SXC + d*25 + q*4+2] = v.z; sm[O_SXC + d*25 + q*4+3] = v.w;
  }
  for (int idx = tid; idx < ROWS*6; idx += 256){
    int r = idx / 6, q = idx - r*6;
    const float* src; float* dst;
    if (r < DTR)        { src = dtpg + r*L_TOT + t0 + q*4;         dst = &sm[O_DTP + r*TCH + q*4]; }
    else if (r < DTR+16){ src = Bg + (r-DTR)*L_TOT + t0 + q*4;     dst = &sm[O_SB + (r-DTR)*25 + q*4]; }
    else                { src = Cg + (r-DTR-16)*L_TOT + t0 + q*4;  dst = &sm[O_SC + (r-DTR-16)*25 + q*4]; }
    float4 v = *reinterpret_cast<const float4*>(src);
    dst[0] = v.x; dst[1] = v.y; dst[2] = v.z; dst[3] = v.w;
  }
  __syncthreads();
  // ---- dt = softplus(dtb + dtw*dtp)
  for (int idx = tid; idx < DI*TCH; idx += 256){
    int d = idx / TCH, j = idx - d*TCH;
    float pre = dtb[d] + dtw[d*DTR]*sm[O_DTP + j];
    if (DTR > 1) pre += dtw[d*DTR + DTR-1]*sm[O_DTP + (DTR-1)*TCH + j];
    sm[O_SDT + d*25 + j] = fsoftplus(pre);
  }
  __syncthreads();

  // ---- pass2 scan: h update + y = sum_s h*C + xc*D -> SY
  {
    const int d  = tid / NSH;
    const int sh = tid - d*NSH;
    float Av[SPB], h[SPB];
#pragma unroll
    for (int j = 0; j < SPB; j++)
      Av[j] = -__expf(Alog[d*16 + sh*SPB + j]);
    {
      const int o = chunk*(DI*16) + tid*SPB;
      if constexpr (SPB == 4){
        float4 hv = *reinterpret_cast<const float4*>(&carry[o]);
        h[0]=hv.x; h[1]=hv.y; h[2]=hv.z; h[3]=hv.w;
      } else {
        float2 hv = *reinterpret_cast<const float2*>(&carry[o]);
        h[0]=hv.x; h[1]=hv.y;
      }
    }
    const float Dv = Dp[d];
    for (int t = 0; t < TCH; t++){
      float dtv = sm[O_SDT + d*25 + t];
      float xcv = sm[O_SXC + d*25 + t];
      float bb2 = dtv*xcv;
      float p = 0.f;
#pragma unroll
      for (int j = 0; j < SPB; j++){
        float a2 = __expf(dtv*Av[j]);
        h[j] = a2*h[j] + bb2*sm[O_SB + (sh*SPB+j)*25 + t];
        p += h[j]*sm[O_SC + (sh*SPB+j)*25 + t];
      }
#pragma unroll
      for (int o = 1; o < NSH; o <<= 1) p += __shfl_xor(p, o);
      if (sh == 0) sm[O_SY + d*25 + t] = p + xcv*Dv;
    }
  }
  __syncthreads();
  // ---- gate: y *= silu(z)   (z streamed from global, never staged)
  for (int idx = tid; idx < DI*6; idx += 256){
    int d = idx / 6, q = idx - d*6;
    float4 zv = *reinterpret_cast<const float4*>(zg + d*L_TOT + t0 + q*4);
    sm[O_SY + d*25 + q*4+0] *= zv.x*fsigmoid(zv.x);
    sm[O_SY + d*25 + q*4+1] *= zv.y*fsigmoid(zv.y);
    sm[O_SY + d*25 + q*4+2] *= zv.z*fsigmoid(zv.z);
    sm[O_SY + d*25 + q*4+3] *= zv.w*fsigmoid(zv.w);
  }
  __syncthreads();

  // ---- out-proj + residual -> padded bf16 conv input
  {
    const int col = tid & 31;
    const int rw  = tid >> 5;        // 8 row-groups
    constexpr int NO = DIM/8;
    float acc[NO];
#pragma unroll
    for (int rr = 0; rr < NO; rr++) acc[rr] = 0.f;
    for (int db = 0; db < DI; db += 16){
      float ycol[16];
#pragma unroll
      for (int k = 0; k < 16; k++) ycol[k] = sm[O_SY + (db+k)*25 + col];
#pragma unroll
      for (int rr = 0; rr < NO; rr++){
        int r = rw + rr*8;
        float a2 = 0.f;
#pragma unroll
        for (int k = 0; k < 16; k++) a2 += ycol[k]*ow[r*DI + db + k];
        acc[rr] += a2;
      }
    }
    if (col < TCH){
      const int t  = t0 + col;
      const int zz = t / 2304;
      const int r2 = t - zz*2304;
      const int yy = r2 / 48;
      const int xx = r2 - yy*48;
      const int pb = (zz+1)*2500 + (yy+1)*50 + (xx+1);
#pragma unroll
      for (int rr = 0; rr < NO; rr++){
        int r = rw + rr*8;
        float res;
        if (RES == 0){
          res = (r < 16) ? r0src[r*L_TOT + t] : r1src[(r-16)*L_TOT + t];
        } else {
          float bm = bstats[2*r]*(1.f/L_TOT);
          float bv = bstats[2*r+1]*(1.f/L_TOT) - bm*bm;
          res = (r0src[r*L_TOT + t] - bm)*rsqrtf(bv+BN_EPS)*bg[r] + bbp[r];
        }
        rp[r*PCH + pb] = f2bf(acc[rr] + res);
      }
    }
  }
}

// ---------------- conv3d via MFMA implicit GEMM + fused BN partial sums -----------
template<int IC>
__global__ __launch_bounds__(256) void k_conv_mfma(const unsigned short* __restrict__ bin,
                         const unsigned short* __restrict__ wA,
                         const float* __restrict__ bias, float* __restrict__ out,
                         float* __restrict__ stats) {
  constexpr int NKB = (IC==32) ? 27 : 14;
  __shared__ float sred[32];
  if (threadIdx.x < 32) sred[threadIdx.x] = 0.f;
  __syncthreads();
  const int lane = threadIdx.x & 63;
  const int n = lane & 15, quad = lane >> 4;
  const int tile = blockIdx.x*4 + (threadIdx.x >> 6);
  const int t = tile*16 + n;
  int zz = t / 2304;
  int r2 = t - zz*2304;
  int yy = r2 / 48;
  int xx = r2 - yy*48;
  int pb = (zz+1)*2500 + (yy+1)*50 + (xx+1);
  const unsigned short* bp[8];
#pragma unroll
  for (int j=0;j<8;j++){
    int e = quad*8 + j;
    int ic = (IC==32) ? e : (e & 15);
    bp[j] = bin + ic*PCH + pb;
  }
  const int rq = (IC==32) ? 0 : (quad >> 1);
  f32x4 acc = {0.f, 0.f, 0.f, 0.f};
#pragma unroll
  for (int kb=0; kb<NKB; kb++){
    bf16x8 af = *reinterpret_cast<const bf16x8*>(wA + (size_t)((kb*4+quad)*16 + n)*8);
    int off;
    if (IC==32) off = off3c(kb);
    else        off = rq ? off3c(2*kb+1) : off3c(2*kb);
    bf16x8 bf;
#pragma unroll
    for (int j=0;j<8;j++) bf[j] = (short)bp[j][off];
    acc = __builtin_amdgcn_mfma_f32_16x16x32_bf16(af, bf, acc, 0, 0, 0);
  }
  float vs[4];
#pragma unroll
  for (int reg=0; reg<4; reg++){
    int m = quad*4 + reg;
    float v = acc[reg] + bias[m];
    out[m*L_TOT + t] = v;
    vs[reg] = v;
  }
#pragma unroll
  for (int reg=0; reg<4; reg++){
    float a = vs[reg], b2 = vs[reg]*vs[reg];
#pragma unroll
    for (int o=1; o<16; o<<=1){ a += __shfl_xor(a,o); b2 += __shfl_xor(b2,o); }
    if (n == 0){
      atomicAdd(&sred[quad*4+reg], a);
      atomicAdd(&sred[16 + quad*4+reg], b2);
    }
  }
  __syncthreads();
  if (threadIdx.x < 16){
    atomicAdd(&stats[2*threadIdx.x],   sred[threadIdx.x]);
    atomicAdd(&stats[2*threadIdx.x+1], sred[16+threadIdx.x]);
  }
}

// ---------------- BN normalize, float4 --------------------------------------------
__global__ void k_bn_norm4(const float* __restrict__ raw, const float* __restrict__ stats,
                           const float* __restrict__ g, const float* __restrict__ b,
                           float* __restrict__ out) {
  int i = blockIdx.x*256 + threadIdx.x;         // over 16*L_TOT/4
  int c = i / (L_TOT/4);
  int tq = i - c*(L_TOT/4);
  float m = stats[2*c]*(1.f/L_TOT);
  float v = stats[2*c+1]*(1.f/L_TOT) - m*m;
  float sc = rsqrtf(v+BN_EPS)*g[c];
  float bs = b[c] - m*sc;
  float4 x = *reinterpret_cast<const float4*>(raw + c*L_TOT + tq*4);
  float4 o = make_float4(x.x*sc+bs, x.y*sc+bs, x.z*sc+bs, x.w*sc+bs);
  *reinterpret_cast<float4*>(out + c*L_TOT + tq*4) = o;
}

// =================================================================================
extern "C" void kernel_launch(void* const* d_in, const int* in_sizes, int n_in,
                              void* d_out, int out_size, void* d_ws, size_t ws_size,
                              hipStream_t stream) {
  const float* l        = (const float*)d_in[0];
  const float* s        = (const float*)d_in[1];
  const float* m1_ln_w  = (const float*)d_in[2];
  const float* m1_ln_b  = (const float*)d_in[3];
  const float* m1_in_w  = (const float*)d_in[4];
  const float* m1_cw    = (const float*)d_in[5];
  const float* m1_cb    = (const float*)d_in[6];
  const float* m1_xp_w  = (const float*)d_in[7];
  const float* m1_dt_w  = (const float*)d_in[8];
  const float* m1_dt_b  = (const float*)d_in[9];
  const float* m1_Alog  = (const float*)d_in[10];
  const float* m1_D     = (const float*)d_in[11];
  const float* m1_out_w = (const float*)d_in[12];
  const float* m2_ln_w  = (const float*)d_in[13];
  const float* m2_ln_b  = (const float*)d_in[14];
  const float* m2_in_w  = (const float*)d_in[15];
  const float* m2_cw    = (const float*)d_in[16];
  const float* m2_cb    = (const float*)d_in[17];
  const float* m2_xp_w  = (const float*)d_in[18];
  const float* m2_dt_w  = (const float*)d_in[19];
  const float* m2_dt_b  = (const float*)d_in[20];
  const float* m2_Alog  = (const float*)d_in[21];
  const float* m2_D     = (const float*)d_in[22];
  const float* m2_out_w = (const float*)d_in[23];
  const float* c1_w     = (const float*)d_in[24];
  const float* c1_b     = (const float*)d_in[25];
  const float* bn1_g    = (const float*)d_in[26];
  const float* bn1_b    = (const float*)d_in[27];
  const float* c2_w     = (const float*)d_in[28];
  const float* c2_b     = (const float*)d_in[29];
  const float* bn2_g    = (const float*)d_in[30];
  const float* bn2_b    = (const float*)d_in[31];

  float* ws = (float*)d_ws;
  const size_t L = L_TOT;
  // stage-1 buffers; stage-2 aliases onto dead stage-1 regions
  float* xc1      = ws;               // 64L   (dead after back1)
  float* z1       = ws + 64*L;        // 64L   (dead after back1)
  float* B1       = ws + 128*L;       // 16L   (shared both stages)
  float* C1       = ws + 144*L;       // 16L
  float* dtp1     = ws + 160*L;       // 2L
  float* conv1raw = ws + 162*L;       // 16L   (live through stage 2)
  float* aggA     = ws + 178*L;       // 1536*1024 floats = 42.67L
  float* aggB     = aggA + 1536*1024;
  float* carry    = aggB + 1536*1024; // ends at 306L
  float* stats1   = ws + 306*L;       // 64 floats (stats1 + stats2)
  float* stats2   = stats1 + 32;
  unsigned short* bfin = (unsigned short*)(stats1 + 64);  // 32ch * PCH bf16
  unsigned short* wA1  = bfin + 32*PCH;  // 13824 ushorts
  unsigned short* wA2  = wA1 + 13824;    // 7168 ushorts
  float* xc2      = ws;               // 32L  (aliases dead xc1)
  float* z2       = ws + 32*L;        // 32L  (aliases dead xc1 upper half)
  float* conv2raw = ws + 64*L;        // 16L  (aliases dead z1)

  // ================= stage 1: mamba(dim=32, di=64) + conv1 + bn1(stats) ==========
  k_front<32,64,2,false,true><<<1536,256,0,stream>>>(l, s, stats1, bn1_g, bn1_b,
      m1_ln_w, m1_ln_b, m1_in_w, m1_cw, m1_cb, m1_xp_w, m1_dt_w, m1_dt_b, m1_Alog,
      xc1, z1, dtp1, B1, C1, aggA, aggB,
      c1_w, wA1, c2_w, wA2, stats1, (float*)bfin);
  k_carry<1536><<<128,256,0,stream>>>(aggA, aggB, carry, 1024);
  k_back<32,64,2,0><<<1536,256,0,stream>>>(xc1, z1, dtp1, B1, C1,
      m1_dt_w, m1_dt_b, m1_Alog, m1_D, carry, m1_out_w, l, s,
      stats1, bn1_g, bn1_b, bfin);
  k_conv_mfma<32><<<576,256,0,stream>>>(bfin, wA1, c1_b, conv1raw, stats1);

  // ================= stage 2: mamba(dim=16, di=32) + conv2 + bn2 =================
  k_front<16,32,1,true,false><<<1536,256,0,stream>>>(conv1raw, conv1raw, stats1, bn1_g, bn1_b,
      m2_ln_w, m2_ln_b, m2_in_w, m2_cw, m2_cb, m2_xp_w, m2_dt_w, m2_dt_b, m2_Alog,
      xc2, z2, dtp1, B1, C1, aggA, aggB,
      nullptr, nullptr, nullptr, nullptr, nullptr, nullptr);
  k_carry<1536><<<64,256,0,stream>>>(aggA, aggB, carry, 512);
  k_back<16,32,1,1><<<1536,256,0,stream>>>(xc2, z2, dtp1, B1, C1,
      m2_dt_w, m2_dt_b, m2_Alog, m2_D, carry, m2_out_w, conv1raw, conv1raw,
      stats1, bn1_g, bn1_b, bfin);
  k_conv_mfma<16><<<576,256,0,stream>>>(bfin, wA2, c2_b, conv2raw, stats2);
  k_bn_norm4<<<576,256,0,stream>>>(conv2raw, stats2, bn2_g, bn2_b, (float*)d_out);
}

// Round 11
// 292.155 us; speedup vs baseline: 1.1080x; 1.1080x over previous
//
#include <hip/hip_runtime.h>
#include <math.h>

#define L_TOT 36864
#define BN_EPS 1e-5f
#define PCH 45000   // padded channel stride: 18*50*50

typedef __attribute__((ext_vector_type(8))) short bf16x8;
typedef __attribute__((ext_vector_type(4))) float f32x4;

__device__ __forceinline__ float fsigmoid(float x){ return 1.f/(1.f+__expf(-x)); }
__device__ __forceinline__ float fsoftplus(float x){
  float e = __expf(x);
  return (x>20.f)? x : __logf(1.f+e);
}
__device__ __forceinline__ unsigned short f2bf(float x){
  union { float f; unsigned u; } cv; cv.f = x;
  unsigned r = (cv.u + 0x7FFFu + ((cv.u>>16)&1u)) >> 16;
  return (unsigned short)r;
}
__host__ __device__ constexpr int off3c(int r){
  return (r>=27) ? 0 : ((r/9)-1)*2500 + (((r%9)/3)-1)*50 + ((r%3)-1);
}

// =================================================================================
// k_front: fused LN (+BN-on-read) + in-proj + causal dwconv/SiLU + x-proj + dt +
//          pass1 chunk aggregates.  One block = one chunk of 48 timesteps.
// x is loaded DIRECTLY into registers (per-column, 4-way redundant across row
// groups, L1-absorbed); LN stats computed in-register per thread. This removes
// the old P0/P1 phases and two barriers - x never touches LDS.
// Region0 (DI*64 floats) holds xs(+halo), later aliased by dt (stride 49).
// SETUP=true (stage 1): folds weight pack / bfin halo zero / stats zero.
// =================================================================================
template<int DIM, int DI, int DTR, bool DOBN, bool SETUP>
__global__ __launch_bounds__(256) void k_front(
    const float* __restrict__ x0, const float* __restrict__ x1,
    const float* __restrict__ bstats, const float* __restrict__ bg, const float* __restrict__ bbp,
    const float* __restrict__ lnw, const float* __restrict__ lnb,
    const float* __restrict__ inw,
    const float* __restrict__ cw, const float* __restrict__ cb,
    const float* __restrict__ xpw,
    const float* __restrict__ dtw, const float* __restrict__ dtb,
    const float* __restrict__ Alog,
    float* __restrict__ xcg, float* __restrict__ zg,
    float* __restrict__ dtpg, float* __restrict__ Bg, float* __restrict__ Cg,
    float* __restrict__ aggA, float* __restrict__ aggB,
    const float* __restrict__ cvw1, unsigned short* __restrict__ wA1,
    const float* __restrict__ cvw2, unsigned short* __restrict__ wA2,
    float* __restrict__ stats, float* __restrict__ bfz)
{
  constexpr int TCH  = 48;
  constexpr int ROWS = DTR + 32;
  constexpr int NSH  = 256/DI;        // threads per d-channel in scan
  constexpr int SPB  = 16/NSH;        // states per thread
  constexpr int CH   = DI*16;
  constexpr int R0SZ = DI*64;         // region0: xs+halo (DI*64) / dt (DI*49)
  constexpr int O_SXC = R0SZ;         // DI*49
  constexpr int O_SB  = O_SXC + DI*49;// 16*49
  constexpr int O_SC  = O_SB + 16*49; // 16*49
  constexpr int O_DTP = O_SC + 16*49; // DTR*48
  constexpr int SMEM  = O_DTP + DTR*48 + 64;
  __shared__ float sm[SMEM];

  const int tid   = threadIdx.x;
  const int chunk = blockIdx.x;
  const int t0    = chunk*TCH;

  // ---- folded setup (stage 1): outputs consumed only by later kernels ----------
  if constexpr (SETUP){
    for (int idx = blockIdx.x*256 + tid; idx < 16*PCH; idx += 768*256)
      bfz[idx] = 0.f;                          // zero bf16 halo buffer (32-bit words)
    const int b = blockIdx.x;
    if (b < 4){
      int k = b*256 + tid;
      if (k < 864){
        int ic = k & 31, r = k >> 5;
        for (int m=0;m<16;m++){
          float v = (r < 27) ? cvw1[m*32*27 + ic*27 + r] : 0.f;
          wA1[(((k>>3)*16) + m)*8 + (k&7)] = f2bf(v);
        }
      }
    } else if (b < 6){
      int k = (b-4)*256 + tid;
      if (k < 448){
        int ic = k & 15, r = k >> 4;
        for (int m=0;m<16;m++){
          float v = (r < 27) ? cvw2[m*16*27 + ic*27 + r] : 0.f;
          wA2[(((k>>3)*16) + m)*8 + (k&7)] = f2bf(v);
        }
      }
    } else if (b == 6){
      if (tid < 64) stats[tid] = 0.f;
    }
  }

  // ---- P012 fused: x -> registers (+BN), in-register LN, in-proj ---------------
  // Thread (group rw = tid>>6, col i = tid&63) owns column t = t0-3+i.
  const int i   = tid & 63;
  const int r0w = __builtin_amdgcn_readfirstlane(tid >> 6);
  {
    float xn[DIM];
    const int t = t0 - 3 + i;
    const bool valid = (i < 51 && t >= 0);
#pragma unroll
    for (int c = 0; c < DIM; c++){
      float v = 0.f;
      if (valid){
        if constexpr (DOBN){
          float raw = x0[c*L_TOT + t];
          float bm = bstats[2*c]*(1.f/L_TOT);
          float bv = bstats[2*c+1]*(1.f/L_TOT) - bm*bm;
          v = (raw - bm)*rsqrtf(bv+BN_EPS)*bg[c] + bbp[c];
        } else {
          v = (c < 16) ? x0[c*L_TOT + t] : x1[(c-16)*L_TOT + t];
        }
      }
      xn[c] = v;
    }
    // LayerNorm in registers (redundant across the 4 row-groups - fully parallel)
    float s = 0.f, s2 = 0.f;
#pragma unroll
    for (int c = 0; c < DIM; c++){ s += xn[c]; s2 += xn[c]*xn[c]; }
    float m  = s*(1.f/DIM);
    float var = s2*(1.f/DIM) - m*m;
    float rs = rsqrtf(var + BN_EPS);
#pragma unroll
    for (int c = 0; c < DIM; c++) xn[c] = (xn[c]-m)*rs*lnw[c] + lnb[c];
    // in-proj (row-serial; round-1-verified form)
    for (int r = r0w; r < 2*DI; r += 4){
      float acc = 0.f;
#pragma unroll
      for (int c = 0; c < DIM; c++) acc += xn[c]*inw[r*DIM + c];
      if (r < DI){
        if (i < 51) sm[r*64 + i] = (t0 == 0 && i < 3) ? 0.f : acc;
      } else {
        if (i >= 3 && i < 51) zg[(r-DI)*L_TOT + t0 + i - 3] = acc;
      }
    }
  }
  __syncthreads();

  // ---- P3: causal depthwise conv (kw=4) + SiLU -> SXC
  for (int idx = tid; idx < DI*48; idx += 256){
    int d = idx / 48, j = idx - d*48;
    const float* xr = &sm[d*64 + j];     // xr[k] = xs[t-3+k]
    float acc = cb[d] + cw[d*4+0]*xr[0] + cw[d*4+1]*xr[1]
                      + cw[d*4+2]*xr[2] + cw[d*4+3]*xr[3];
    sm[O_SXC + d*49 + j] = acc * fsigmoid(acc);
  }
  __syncthreads();

  // ---- P4: x-proj -> dtp | B | C
  {
    constexpr int NR = (ROWS + 3) / 4;
    float acc[NR];
#pragma unroll
    for (int rr = 0; rr < NR; rr++) acc[rr] = 0.f;
    for (int db = 0; db < DI; db += 16){
      float xcol[16];
#pragma unroll
      for (int k = 0; k < 16; k++) xcol[k] = sm[O_SXC + (db+k)*49 + i];
#pragma unroll
      for (int rr = 0; rr < NR; rr++){
        int r = r0w + rr*4;
        if (r < ROWS){
          float a2 = 0.f;
#pragma unroll
          for (int k = 0; k < 16; k++) a2 += xcol[k]*xpw[r*DI + db + k];
          acc[rr] += a2;
        }
      }
    }
    if (i < 48){
#pragma unroll
      for (int rr = 0; rr < NR; rr++){
        int r = r0w + rr*4;
        if (r < ROWS){
          if (r < DTR)          sm[O_DTP + r*48 + i] = acc[rr];
          else if (r < DTR+16)  sm[O_SB + (r-DTR)*49 + i] = acc[rr];
          else                  sm[O_SC + (r-DTR-16)*49 + i] = acc[rr];
        }
      }
    }
  }
  __syncthreads();

  // ---- P5: dt = softplus(dtb + dtw*dtp) -> region0 (xs dead)
  for (int idx = tid; idx < DI*48; idx += 256){
    int d = idx / 48, j = idx - d*48;
    float pre = dtb[d] + dtw[d*DTR]*sm[O_DTP + j];
    if (DTR > 1) pre += dtw[d*DTR + DTR-1]*sm[O_DTP + (DTR-1)*48 + j];
    sm[d*49 + j] = fsoftplus(pre);
  }
  __syncthreads();

  // ---- P6: spill xc/dtp/B/C to global, all float4 (stores fly during pass1)
  for (int idx = tid; idx < DI*12; idx += 256){
    int d = idx / 12, q = idx - d*12;
    float4 v = make_float4(sm[O_SXC + d*49 + q*4+0], sm[O_SXC + d*49 + q*4+1],
                           sm[O_SXC + d*49 + q*4+2], sm[O_SXC + d*49 + q*4+3]);
    *reinterpret_cast<float4*>(xcg + d*L_TOT + t0 + q*4) = v;
  }
  for (int idx = tid; idx < ROWS*12; idx += 256){
    int r = idx / 12, q = idx - r*12;
    const float* src; float* dst;
    if (r < DTR)        { src = &sm[O_DTP + r*48 + q*4];          dst = dtpg + r*L_TOT + t0 + q*4; }
    else if (r < DTR+16){ src = &sm[O_SB + (r-DTR)*49 + q*4];     dst = Bg + (r-DTR)*L_TOT + t0 + q*4; }
    else                { src = &sm[O_SC + (r-DTR-16)*49 + q*4];  dst = Cg + (r-DTR-16)*L_TOT + t0 + q*4; }
    *reinterpret_cast<float4*>(dst) = make_float4(src[0], src[1], src[2], src[3]);
  }

  // ---- P7: pass1 scan -> per-chunk (A,B) aggregates
  {
    const int d  = tid / NSH;
    const int sh = tid - d*NSH;
    float Av[SPB], Ar[SPB], Br[SPB];
#pragma unroll
    for (int j = 0; j < SPB; j++){
      Av[j] = -__expf(Alog[d*16 + sh*SPB + j]);
      Ar[j] = 1.f; Br[j] = 0.f;
    }
    for (int t = 0; t < TCH; t++){
      float dtv = sm[d*49 + t];
      float bb2 = dtv * sm[O_SXC + d*49 + t];
#pragma unroll
      for (int j = 0; j < SPB; j++){
        float a2 = __expf(dtv*Av[j]);
        Ar[j] *= a2;
        Br[j] = a2*Br[j] + bb2*sm[O_SB + (sh*SPB+j)*49 + t];
      }
    }
    const int o = chunk*CH + tid*SPB;
    if constexpr (SPB == 4){
      *reinterpret_cast<float4*>(&aggA[o]) = make_float4(Ar[0],Ar[1],Ar[2],Ar[3]);
      *reinterpret_cast<float4*>(&aggB[o]) = make_float4(Br[0],Br[1],Br[2],Br[3]);
    } else {
      *reinterpret_cast<float2*>(&aggA[o]) = make_float2(Ar[0],Ar[1]);
      *reinterpret_cast<float2*>(&aggB[o]) = make_float2(Br[0],Br[1]);
    }
  }
}

// ---------------- parallel scan over chunk aggregates -> carries ------------------
// 16 channels x 16 segments per 256-thread block; grid = CH/16 blocks.
template<int NCH>
__global__ __launch_bounds__(256) void k_carry(const float* __restrict__ aggA,
                        const float* __restrict__ aggB,
                        float* __restrict__ carry, int CH) {
  constexpr int SEG = NCH/16;         // 48 chunks per segment
  const int chl = threadIdx.x & 15;
  const int seg = threadIdx.x >> 4;
  const int ch  = blockIdx.x*16 + chl;
  const int c0  = seg*SEG;
  float a = 1.f, b = 0.f;
  for (int cb=c0; cb<c0+SEG; cb+=8){
    float av[8], bv[8];
#pragma unroll
    for (int k=0;k<8;k++){ av[k]=aggA[(cb+k)*CH+ch]; bv[k]=aggB[(cb+k)*CH+ch]; }
#pragma unroll
    for (int k=0;k<8;k++){ a = a*av[k]; b = av[k]*b + bv[k]; }
  }
  __shared__ float sa[16][17], sb[16][17];
  sa[seg][chl]=a; sb[seg][chl]=b;
  __syncthreads();
  if (threadIdx.x < 16){
    float pa=1.f, pb=0.f;
    for (int g=0; g<16; g++){
      float ca=sa[g][threadIdx.x], cb2=sb[g][threadIdx.x];
      sa[g][threadIdx.x]=pa; sb[g][threadIdx.x]=pb;
      float na = pa*ca;
      float nb = ca*pb + cb2;
      pa=na; pb=nb;
    }
  }
  __syncthreads();
  float h = sb[seg][chl];
  for (int cb=c0; cb<c0+SEG; cb+=8){
    float av[8], bv[8];
#pragma unroll
    for (int k=0;k<8;k++){ av[k]=aggA[(cb+k)*CH+ch]; bv[k]=aggB[(cb+k)*CH+ch]; }
#pragma unroll
    for (int k=0;k<8;k++){ carry[(cb+k)*CH+ch]=h; h = av[k]*h + bv[k]; }
  }
}

// =================================================================================
// k_back: fused pass2 scan + z-gate + out-proj + residual -> bf16 padded layout.
// =================================================================================
template<int DIM, int DI, int DTR, int RES>
__global__ __launch_bounds__(256) void k_back(
    const float* __restrict__ xcg, const float* __restrict__ zg,
    const float* __restrict__ dtpg, const float* __restrict__ Bg, const float* __restrict__ Cg,
    const float* __restrict__ dtw, const float* __restrict__ dtb,
    const float* __restrict__ Alog, const float* __restrict__ Dp,
    const float* __restrict__ carry,
    const float* __restrict__ ow,
    const float* __restrict__ r0src, const float* __restrict__ r1src,
    const float* __restrict__ bstats, const float* __restrict__ bg, const float* __restrict__ bbp,
    unsigned short* __restrict__ rp)
{
  constexpr int TCH = 48;
  constexpr int NSH = 256/DI;
  constexpr int SPB = 16/NSH;
  constexpr int ROWS = DTR + 32;
  constexpr int O_SXC = 0;               // DI*49
  constexpr int O_SDT = O_SXC + DI*49;   // DI*49
  constexpr int O_SB  = O_SDT + DI*49;   // 16*49
  constexpr int O_SC  = O_SB + 16*49;    // 16*49
  constexpr int O_SY  = O_SC + 16*49;    // DI*49
  constexpr int O_DTP = O_SY + DI*49;    // DTR*48
  constexpr int SMEM  = O_DTP + DTR*48 + 64;
  __shared__ float sm[SMEM];
  const int tid   = threadIdx.x;
  const int chunk = blockIdx.x;
  const int t0    = chunk*TCH;

  // ---- load xc / B / C / dtp (float4 global, scalar LDS scatter)
  for (int idx = tid; idx < DI*12; idx += 256){
    int d = idx / 12, q = idx - d*12;
    float4 v = *reinterpret_cast<const float4*>(xcg + d*L_TOT + t0 + q*4);
    sm[O_SXC + d*49 + q*4+0] = v.x; sm[O_SXC + d*49 + q*4+1] = v.y;
    sm[O_SXC + d*49 + q*4+2] = v.z; sm[O_SXC + d*49 + q*4+3] = v.w;
  }
  for (int idx = tid; idx < ROWS*12; idx += 256){
    int r = idx / 12, q = idx - r*12;
    const float* src; float* dst;
    if (r < DTR)        { src = dtpg + r*L_TOT + t0 + q*4;         dst = &sm[O_DTP + r*48 + q*4]; }
    else if (r < DTR+16){ src = Bg + (r-DTR)*L_TOT + t0 + q*4;     dst = &sm[O_SB + (r-DTR)*49 + q*4]; }
    else                { src = Cg + (r-DTR-16)*L_TOT + t0 + q*4;  dst = &sm[O_SC + (r-DTR-16)*49 + q*4]; }
    float4 v = *reinterpret_cast<const float4*>(src);
    dst[0] = v.x; dst[1] = v.y; dst[2] = v.z; dst[3] = v.w;
  }
  __syncthreads();
  // ---- dt = softplus(dtb + dtw*dtp)
  for (int idx = tid; idx < DI*48; idx += 256){
    int d = idx / 48, j = idx - d*48;
    float pre = dtb[d] + dtw[d*DTR]*sm[O_DTP + j];
    if (DTR > 1) pre += dtw[d*DTR + DTR-1]*sm[O_DTP + 48 + j];
    sm[O_SDT + d*49 + j] = fsoftplus(pre);
  }
  __syncthreads();

  // ---- pass2 scan: h update + y = sum_s h*C + xc*D -> SY
  {
    const int d  = tid / NSH;
    const int sh = tid - d*NSH;
    float Av[SPB], h[SPB];
#pragma unroll
    for (int j = 0; j < SPB; j++){
      Av[j] = -__expf(Alog[d*16 + sh*SPB + j]);
      h[j]  = carry[chunk*(DI*16) + tid*SPB + j];
    }
    const float Dv = Dp[d];
    for (int t = 0; t < TCH; t++){
      float dtv = sm[O_SDT + d*49 + t];
      float xcv = sm[O_SXC + d*49 + t];
      float bb2 = dtv*xcv;
      float p = 0.f;
#pragma unroll
      for (int j = 0; j < SPB; j++){
        float a2 = __expf(dtv*Av[j]);
        h[j] = a2*h[j] + bb2*sm[O_SB + (sh*SPB+j)*49 + t];
        p += h[j]*sm[O_SC + (sh*SPB+j)*49 + t];
      }
#pragma unroll
      for (int o = 1; o < NSH; o <<= 1) p += __shfl_xor(p, o);
      if (sh == 0) sm[O_SY + d*49 + t] = p + xcv*Dv;
    }
  }
  __syncthreads();
  // ---- gate: y *= silu(z)   (z streamed from global, never staged)
  for (int idx = tid; idx < DI*12; idx += 256){
    int d = idx / 12, q = idx - d*12;
    float4 zv = *reinterpret_cast<const float4*>(zg + d*L_TOT + t0 + q*4);
    sm[O_SY + d*49 + q*4+0] *= zv.x*fsigmoid(zv.x);
    sm[O_SY + d*49 + q*4+1] *= zv.y*fsigmoid(zv.y);
    sm[O_SY + d*49 + q*4+2] *= zv.z*fsigmoid(zv.z);
    sm[O_SY + d*49 + q*4+3] *= zv.w*fsigmoid(zv.w);
  }
  __syncthreads();

  // ---- out-proj + residual -> padded bf16 conv input
  {
    const int col = tid & 63;
    const int r0w = __builtin_amdgcn_readfirstlane(tid >> 6);
    constexpr int NO = DIM/4;
    float acc[NO];
#pragma unroll
    for (int rr = 0; rr < NO; rr++) acc[rr] = 0.f;
    for (int db = 0; db < DI; db += 16){
      float ycol[16];
#pragma unroll
      for (int k = 0; k < 16; k++) ycol[k] = sm[O_SY + (db+k)*49 + col];
#pragma unroll
      for (int rr = 0; rr < NO; rr++){
        int r = r0w + rr*4;
        float a2 = 0.f;
#pragma unroll
        for (int k = 0; k < 16; k++) a2 += ycol[k]*ow[r*DI + db + k];
        acc[rr] += a2;
      }
    }
    if (col < 48){
      const int t  = t0 + col;
      const int zz = chunk / 48, yy = chunk - zz*48;     // 48 cols = one (zz,yy) row
      const int pb = (zz+1)*2500 + (yy+1)*50 + (col+1);
#pragma unroll
      for (int rr = 0; rr < NO; rr++){
        int r = r0w + rr*4;
        float res;
        if (RES == 0){
          res = (r < 16) ? r0src[r*L_TOT + t] : r1src[(r-16)*L_TOT + t];
        } else {
          float bm = bstats[2*r]*(1.f/L_TOT);
          float bv = bstats[2*r+1]*(1.f/L_TOT) - bm*bm;
          res = (r0src[r*L_TOT + t] - bm)*rsqrtf(bv+BN_EPS)*bg[r] + bbp[r];
        }
        rp[r*PCH + pb] = f2bf(acc[rr] + res);
      }
    }
  }
}

// ---------------- conv3d via MFMA implicit GEMM + fused BN partial sums -----------
template<int IC>
__global__ __launch_bounds__(256) void k_conv_mfma(const unsigned short* __restrict__ bin,
                         const unsigned short* __restrict__ wA,
                         const float* __restrict__ bias, float* __restrict__ out,
                         float* __restrict__ stats) {
  constexpr int NKB = (IC==32) ? 27 : 14;
  __shared__ float sred[32];
  if (threadIdx.x < 32) sred[threadIdx.x] = 0.f;
  __syncthreads();
  const int lane = threadIdx.x & 63;
  const int n = lane & 15, quad = lane >> 4;
  const int tile = blockIdx.x*4 + (threadIdx.x >> 6);
  const int t = tile*16 + n;
  int zz = t / 2304;
  int r2 = t - zz*2304;
  int yy = r2 / 48;
  int xx = r2 - yy*48;
  int pb = (zz+1)*2500 + (yy+1)*50 + (xx+1);
  const unsigned short* bp[8];
#pragma unroll
  for (int j=0;j<8;j++){
    int e = quad*8 + j;
    int ic = (IC==32) ? e : (e & 15);
    bp[j] = bin + ic*PCH + pb;
  }
  const int rq = (IC==32) ? 0 : (quad >> 1);
  f32x4 acc = {0.f, 0.f, 0.f, 0.f};
#pragma unroll
  for (int kb=0; kb<NKB; kb++){
    bf16x8 af = *reinterpret_cast<const bf16x8*>(wA + (size_t)((kb*4+quad)*16 + n)*8);
    int off;
    if (IC==32) off = off3c(kb);
    else        off = rq ? off3c(2*kb+1) : off3c(2*kb);
    bf16x8 bf;
#pragma unroll
    for (int j=0;j<8;j++) bf[j] = (short)bp[j][off];
    acc = __builtin_amdgcn_mfma_f32_16x16x32_bf16(af, bf, acc, 0, 0, 0);
  }
  float vs[4];
#pragma unroll
  for (int reg=0; reg<4; reg++){
    int m = quad*4 + reg;
    float v = acc[reg] + bias[m];
    out[m*L_TOT + t] = v;
    vs[reg] = v;
  }
#pragma unroll
  for (int reg=0; reg<4; reg++){
    float a = vs[reg], b2 = vs[reg]*vs[reg];
#pragma unroll
    for (int o=1; o<16; o<<=1){ a += __shfl_xor(a,o); b2 += __shfl_xor(b2,o); }
    if (n == 0){
      atomicAdd(&sred[quad*4+reg], a);
      atomicAdd(&sred[16 + quad*4+reg], b2);
    }
  }
  __syncthreads();
  if (threadIdx.x < 16){
    atomicAdd(&stats[2*threadIdx.x],   sred[threadIdx.x]);
    atomicAdd(&stats[2*threadIdx.x+1], sred[16+threadIdx.x]);
  }
}

// ---------------- BN normalize, float4 --------------------------------------------
__global__ void k_bn_norm4(const float* __restrict__ raw, const float* __restrict__ stats,
                           const float* __restrict__ g, const float* __restrict__ b,
                           float* __restrict__ out) {
  int i = blockIdx.x*256 + threadIdx.x;         // over 16*L_TOT/4
  int c = i / (L_TOT/4);
  int tq = i - c*(L_TOT/4);
  float m = stats[2*c]*(1.f/L_TOT);
  float v = stats[2*c+1]*(1.f/L_TOT) - m*m;
  float sc = rsqrtf(v+BN_EPS)*g[c];
  float bs = b[c] - m*sc;
  float4 x = *reinterpret_cast<const float4*>(raw + c*L_TOT + tq*4);
  float4 o = make_float4(x.x*sc+bs, x.y*sc+bs, x.z*sc+bs, x.w*sc+bs);
  *reinterpret_cast<float4*>(out + c*L_TOT + tq*4) = o;
}

// =================================================================================
extern "C" void kernel_launch(void* const* d_in, const int* in_sizes, int n_in,
                              void* d_out, int out_size, void* d_ws, size_t ws_size,
                              hipStream_t stream) {
  const float* l        = (const float*)d_in[0];
  const float* s        = (const float*)d_in[1];
  const float* m1_ln_w  = (const float*)d_in[2];
  const float* m1_ln_b  = (const float*)d_in[3];
  const float* m1_in_w  = (const float*)d_in[4];
  const float* m1_cw    = (const float*)d_in[5];
  const float* m1_cb    = (const float*)d_in[6];
  const float* m1_xp_w  = (const float*)d_in[7];
  const float* m1_dt_w  = (const float*)d_in[8];
  const float* m1_dt_b  = (const float*)d_in[9];
  const float* m1_Alog  = (const float*)d_in[10];
  const float* m1_D     = (const float*)d_in[11];
  const float* m1_out_w = (const float*)d_in[12];
  const float* m2_ln_w  = (const float*)d_in[13];
  const float* m2_ln_b  = (const float*)d_in[14];
  const float* m2_in_w  = (const float*)d_in[15];
  const float* m2_cw    = (const float*)d_in[16];
  const float* m2_cb    = (const float*)d_in[17];
  const float* m2_xp_w  = (const float*)d_in[18];
  const float* m2_dt_w  = (const float*)d_in[19];
  const float* m2_dt_b  = (const float*)d_in[20];
  const float* m2_Alog  = (const float*)d_in[21];
  const float* m2_D     = (const float*)d_in[22];
  const float* m2_out_w = (const float*)d_in[23];
  const float* c1_w     = (const float*)d_in[24];
  const float* c1_b     = (const float*)d_in[25];
  const float* bn1_g    = (const float*)d_in[26];
  const float* bn1_b    = (const float*)d_in[27];
  const float* c2_w     = (const float*)d_in[28];
  const float* c2_b     = (const float*)d_in[29];
  const float* bn2_g    = (const float*)d_in[30];
  const float* bn2_b    = (const float*)d_in[31];

  float* ws = (float*)d_ws;
  const size_t L = L_TOT;
  float* xc1      = ws;               // 64L
  float* z1       = ws + 64*L;        // 64L
  float* B1       = ws + 128*L;       // 16L   (reused by stage 2)
  float* C1       = ws + 144*L;       // 16L   (reused by stage 2)
  float* dtp1     = ws + 160*L;       // 2L    (reused by stage 2)
  float* conv1raw = ws + 162*L;       // 16L
  float* xc2      = ws + 178*L;       // 32L
  float* z2       = ws + 210*L;       // 32L
  float* conv2raw = ws + 242*L;       // 16L
  float* aggA     = ws + 258*L;       // 786432
  float* aggB     = aggA + 786432;
  float* carry    = aggB + 786432;    // ends at 322L
  float* stats1   = ws + 322*L;       // 32
  float* stats2   = stats1 + 32;      // 32
  unsigned short* bfin = (unsigned short*)(ws + 323*L);   // 32ch * PCH bf16
  unsigned short* wA1  = (unsigned short*)(ws + 343*L);   // 13824
  unsigned short* wA2  = wA1 + 13824;                     // 7168

  // ================= stage 1: mamba(dim=32, di=64) + conv1 + bn1(stats) ==========
  // k_front<...,SETUP=true> also performs the old k_setup work (weight pack, bfin
  // halo zero, stats zero) - all consumed only by later kernels in stream order.
  k_front<32,64,2,false,true><<<768,256,0,stream>>>(l, s, stats1, bn1_g, bn1_b,
      m1_ln_w, m1_ln_b, m1_in_w, m1_cw, m1_cb, m1_xp_w, m1_dt_w, m1_dt_b, m1_Alog,
      xc1, z1, dtp1, B1, C1, aggA, aggB,
      c1_w, wA1, c2_w, wA2, stats1, (float*)bfin);
  k_carry<768><<<64,256,0,stream>>>(aggA, aggB, carry, 1024);
  k_back<32,64,2,0><<<768,256,0,stream>>>(xc1, z1, dtp1, B1, C1,
      m1_dt_w, m1_dt_b, m1_Alog, m1_D, carry, m1_out_w, l, s,
      stats1, bn1_g, bn1_b, bfin);
  k_conv_mfma<32><<<576,256,0,stream>>>(bfin, wA1, c1_b, conv1raw, stats1);

  // ================= stage 2: mamba(dim=16, di=32) + conv2 + bn2 =================
  k_front<16,32,1,true,false><<<768,256,0,stream>>>(conv1raw, conv1raw, stats1, bn1_g, bn1_b,
      m2_ln_w, m2_ln_b, m2_in_w, m2_cw, m2_cb, m2_xp_w, m2_dt_w, m2_dt_b, m2_Alog,
      xc2, z2, dtp1, B1, C1, aggA, aggB,
      nullptr, nullptr, nullptr, nullptr, nullptr, nullptr);
  k_carry<768><<<32,256,0,stream>>>(aggA, aggB, carry, 512);
  k_back<16,32,1,1><<<768,256,0,stream>>>(xc2, z2, dtp1, B1, C1,
      m2_dt_w, m2_dt_b, m2_Alog, m2_D, carry, m2_out_w, conv1raw, conv1raw,
      stats1, bn1_g, bn1_b, bfin);
  k_conv_mfma<16><<<576,256,0,stream>>>(bfin, wA2, c2_b, conv2raw, stats2);
  k_bn_norm4<<<576,256,0,stream>>>(conv2raw, stats2, bn2_g, bn2_b, (float*)d_out);
}

// Round 12
// 283.064 us; speedup vs baseline: 1.1436x; 1.0321x over previous
//
#include <hip/hip_runtime.h>
#include <math.h>

#define L_TOT 36864
#define BN_EPS 1e-5f
#define PCH 45000   // padded channel stride: 18*50*50

typedef __attribute__((ext_vector_type(8))) short bf16x8;
typedef __attribute__((ext_vector_type(4))) float f32x4;

__device__ __forceinline__ float fsigmoid(float x){ return 1.f/(1.f+__expf(-x)); }
__device__ __forceinline__ float fsoftplus(float x){
  float e = __expf(x);
  return (x>20.f)? x : __logf(1.f+e);
}
__device__ __forceinline__ unsigned short f2bf(float x){
  union { float f; unsigned u; } cv; cv.f = x;
  unsigned r = (cv.u + 0x7FFFu + ((cv.u>>16)&1u)) >> 16;
  return (unsigned short)r;
}
__host__ __device__ constexpr int off3c(int r){
  return (r>=27) ? 0 : ((r/9)-1)*2500 + (((r%9)/3)-1)*50 + ((r%3)-1);
}

// =================================================================================
// k_front: fused LN (+BN-on-read) + MFMA in-proj + causal dwconv/SiLU + x-proj +
//          dt + pass1 chunk aggregates.  One block = one chunk of 48 timesteps.
// In-proj runs on the matrix cores: per block, inw is packed to bf16 A-frags in
// LDS (layout identical to the proven k_conv_mfma operands), post-LN xn is written
// as a bf16 B-panel (aliasing the dead SXC region), and each wave computes one
// 16-col tile x (2*DI/16) row-tiles of D = inw x xn with f32 accumulation.
// Region0 (DI*64 floats) holds xs(+halo), later aliased by dt (stride 49).
// SETUP=true (stage 1): folds conv-weight pack / bfin halo zero / stats zero.
// =================================================================================
template<int DIM, int DI, int DTR, bool DOBN, bool SETUP>
__global__ __launch_bounds__(256) void k_front(
    const float* __restrict__ x0, const float* __restrict__ x1,
    const float* __restrict__ bstats, const float* __restrict__ bg, const float* __restrict__ bbp,
    const float* __restrict__ lnw, const float* __restrict__ lnb,
    const float* __restrict__ inw,
    const float* __restrict__ cw, const float* __restrict__ cb,
    const float* __restrict__ xpw,
    const float* __restrict__ dtw, const float* __restrict__ dtb,
    const float* __restrict__ Alog,
    float* __restrict__ xcg, float* __restrict__ zg,
    float* __restrict__ dtpg, float* __restrict__ Bg, float* __restrict__ Cg,
    float* __restrict__ aggA, float* __restrict__ aggB,
    const float* __restrict__ cvw1, unsigned short* __restrict__ wA1,
    const float* __restrict__ cvw2, unsigned short* __restrict__ wA2,
    float* __restrict__ stats, float* __restrict__ bfz)
{
  constexpr int TCH  = 48;
  constexpr int ROWS = DTR + 32;
  constexpr int NSH  = 256/DI;        // threads per d-channel in scan
  constexpr int SPB  = 16/NSH;        // states per thread
  constexpr int CH   = DI*16;
  constexpr int NRT  = (2*DI)/16;     // MFMA row-tiles for in-proj (8 / 4)
  constexpr int R0SZ = DI*64;         // region0: xs+halo (DI*64) / dt (DI*49)
  constexpr int O_SXC = R0SZ;         // DI*49  (also aliases bf16 xn panel pre-P3)
  constexpr int O_SB  = O_SXC + DI*49;// 16*49
  constexpr int O_SC  = O_SB + 16*49; // 16*49
  constexpr int O_DTP = O_SC + 16*49; // DTR*48
  constexpr int O_WA  = O_DTP + DTR*48;       // in-proj A-frags: NRT*256 floats
  constexpr int SMEM  = O_WA + NRT*256 + 16;
  __shared__ float sm[SMEM];

  const int tid   = threadIdx.x;
  const int chunk = blockIdx.x;
  const int t0    = chunk*TCH;

  // ---- folded setup (stage 1): outputs consumed only by later kernels ----------
  if constexpr (SETUP){
    for (int idx = blockIdx.x*256 + tid; idx < 16*PCH; idx += 768*256)
      bfz[idx] = 0.f;                          // zero bf16 halo buffer (32-bit words)
    const int b = blockIdx.x;
    if (b < 4){
      int k = b*256 + tid;
      if (k < 864){
        int ic = k & 31, r = k >> 5;
        for (int m=0;m<16;m++){
          float v = (r < 27) ? cvw1[m*32*27 + ic*27 + r] : 0.f;
          wA1[(((k>>3)*16) + m)*8 + (k&7)] = f2bf(v);
        }
      }
    } else if (b < 6){
      int k = (b-4)*256 + tid;
      if (k < 448){
        int ic = k & 15, r = k >> 4;
        for (int m=0;m<16;m++){
          float v = (r < 27) ? cvw2[m*16*27 + ic*27 + r] : 0.f;
          wA2[(((k>>3)*16) + m)*8 + (k&7)] = f2bf(v);
        }
      }
    } else if (b == 6){
      if (tid < 64) stats[tid] = 0.f;
    }
  }

  const int i   = tid & 63;
  const int r0w = __builtin_amdgcn_readfirstlane(tid >> 6);

  // ---- P012: pack inw A-frags -> LDS; x -> regs (+BN) -> LN -> bf16 B-panel ----
  {
    unsigned short* winAl = (unsigned short*)&sm[O_WA];
    unsigned short* xnl   = (unsigned short*)&sm[O_SXC];   // 64 cols x 32 k (bf16)
    // pack in-proj weights into MFMA A-frag layout (K zero-padded to 32)
    for (int sidx = tid; sidx < NRT*64; sidx += 256){
      int ln  = sidx & 63;
      int row = (sidx >> 6)*16 + (ln & 15);
      int k0  = (ln >> 4)*8;
      unsigned short* wp = winAl + sidx*8;
#pragma unroll
      for (int j = 0; j < 8; j++){
        int k = k0 + j;
        wp[j] = (k < DIM) ? f2bf(inw[row*DIM + k]) : (unsigned short)0;
      }
    }
    // x -> registers (column t = t0-3+i), optional BN, in-register LayerNorm
    float xn[DIM];
    const int t = t0 - 3 + i;
    const bool valid = (i < 51 && t >= 0);
#pragma unroll
    for (int c = 0; c < DIM; c++){
      float v = 0.f;
      if (valid){
        if constexpr (DOBN){
          float raw = x0[c*L_TOT + t];
          float bm = bstats[2*c]*(1.f/L_TOT);
          float bv = bstats[2*c+1]*(1.f/L_TOT) - bm*bm;
          v = (raw - bm)*rsqrtf(bv+BN_EPS)*bg[c] + bbp[c];
        } else {
          v = (c < 16) ? x0[c*L_TOT + t] : x1[(c-16)*L_TOT + t];
        }
      }
      xn[c] = v;
    }
    float s = 0.f, s2 = 0.f;
#pragma unroll
    for (int c = 0; c < DIM; c++){ s += xn[c]; s2 += xn[c]*xn[c]; }
    float m  = s*(1.f/DIM);
    float var = s2*(1.f/DIM) - m*m;
    float rs = rsqrtf(var + BN_EPS);
    // bf16 B-panel: xnl[col][k], K zero-padded to 32
    unsigned short* xr = xnl + i*32;
#pragma unroll
    for (int c = 0; c < DIM; c++) xr[c] = f2bf((xn[c]-m)*rs*lnw[c] + lnb[c]);
    if constexpr (DIM < 32){
#pragma unroll
      for (int c = DIM; c < 32; c++) xr[c] = 0;
    }
  }
  __syncthreads();

  // ---- P2-MFMA: in-proj D = inw x xn.  wave = 16-col tile, 8/4 row-tiles -------
  {
    const unsigned short* winAl = (const unsigned short*)&sm[O_WA];
    const unsigned short* xnl   = (const unsigned short*)&sm[O_SXC];
    const int ln  = tid & 63;
    const int wv  = tid >> 6;              // col-tile
    const int col = wv*16 + (ln & 15);
    bf16x8 bfr = *reinterpret_cast<const bf16x8*>(xnl + (size_t)col*32 + (ln>>4)*8);
    f32x4 zero = {0.f,0.f,0.f,0.f};
#pragma unroll
    for (int rt = 0; rt < NRT; rt++){
      bf16x8 af = *reinterpret_cast<const bf16x8*>(winAl + (size_t)(rt*64 + ln)*8);
      f32x4 dd = __builtin_amdgcn_mfma_f32_16x16x32_bf16(af, bfr, zero, 0, 0, 0);
#pragma unroll
      for (int r = 0; r < 4; r++){
        int row = rt*16 + (ln>>4)*4 + r;
        if (row < DI){
          if (col < 51) sm[row*64 + col] = (t0 == 0 && col < 3) ? 0.f : dd[r];
        } else {
          if (col >= 3 && col < 51) zg[(row-DI)*L_TOT + t0 + col - 3] = dd[r];
        }
      }
    }
  }
  __syncthreads();

  // ---- P3: causal depthwise conv (kw=4) + SiLU -> SXC
  for (int idx = tid; idx < DI*48; idx += 256){
    int d = idx / 48, j = idx - d*48;
    const float* xr = &sm[d*64 + j];     // xr[k] = xs[t-3+k]
    float acc = cb[d] + cw[d*4+0]*xr[0] + cw[d*4+1]*xr[1]
                      + cw[d*4+2]*xr[2] + cw[d*4+3]*xr[3];
    sm[O_SXC + d*49 + j] = acc * fsigmoid(acc);
  }
  __syncthreads();

  // ---- P4: x-proj -> dtp | B | C
  {
    constexpr int NR = (ROWS + 3) / 4;
    float acc[NR];
#pragma unroll
    for (int rr = 0; rr < NR; rr++) acc[rr] = 0.f;
    for (int db = 0; db < DI; db += 16){
      float xcol[16];
#pragma unroll
      for (int k = 0; k < 16; k++) xcol[k] = sm[O_SXC + (db+k)*49 + i];
#pragma unroll
      for (int rr = 0; rr < NR; rr++){
        int r = r0w + rr*4;
        if (r < ROWS){
          float a2 = 0.f;
#pragma unroll
          for (int k = 0; k < 16; k++) a2 += xcol[k]*xpw[r*DI + db + k];
          acc[rr] += a2;
        }
      }
    }
    if (i < 48){
#pragma unroll
      for (int rr = 0; rr < NR; rr++){
        int r = r0w + rr*4;
        if (r < ROWS){
          if (r < DTR)          sm[O_DTP + r*48 + i] = acc[rr];
          else if (r < DTR+16)  sm[O_SB + (r-DTR)*49 + i] = acc[rr];
          else                  sm[O_SC + (r-DTR-16)*49 + i] = acc[rr];
        }
      }
    }
  }
  __syncthreads();

  // ---- P5: dt = softplus(dtb + dtw*dtp) -> region0 (xs dead)
  for (int idx = tid; idx < DI*48; idx += 256){
    int d = idx / 48, j = idx - d*48;
    float pre = dtb[d] + dtw[d*DTR]*sm[O_DTP + j];
    if (DTR > 1) pre += dtw[d*DTR + DTR-1]*sm[O_DTP + (DTR-1)*48 + j];
    sm[d*49 + j] = fsoftplus(pre);
  }
  __syncthreads();

  // ---- P6: spill xc/dtp/B/C to global, all float4 (stores fly during pass1)
  for (int idx = tid; idx < DI*12; idx += 256){
    int d = idx / 12, q = idx - d*12;
    float4 v = make_float4(sm[O_SXC + d*49 + q*4+0], sm[O_SXC + d*49 + q*4+1],
                           sm[O_SXC + d*49 + q*4+2], sm[O_SXC + d*49 + q*4+3]);
    *reinterpret_cast<float4*>(xcg + d*L_TOT + t0 + q*4) = v;
  }
  for (int idx = tid; idx < ROWS*12; idx += 256){
    int r = idx / 12, q = idx - r*12;
    const float* src; float* dst;
    if (r < DTR)        { src = &sm[O_DTP + r*48 + q*4];          dst = dtpg + r*L_TOT + t0 + q*4; }
    else if (r < DTR+16){ src = &sm[O_SB + (r-DTR)*49 + q*4];     dst = Bg + (r-DTR)*L_TOT + t0 + q*4; }
    else                { src = &sm[O_SC + (r-DTR-16)*49 + q*4];  dst = Cg + (r-DTR-16)*L_TOT + t0 + q*4; }
    *reinterpret_cast<float4*>(dst) = make_float4(src[0], src[1], src[2], src[3]);
  }

  // ---- P7: pass1 scan -> per-chunk (A,B) aggregates
  {
    const int d  = tid / NSH;
    const int sh = tid - d*NSH;
    float Av[SPB], Ar[SPB], Br[SPB];
#pragma unroll
    for (int j = 0; j < SPB; j++){
      Av[j] = -__expf(Alog[d*16 + sh*SPB + j]);
      Ar[j] = 1.f; Br[j] = 0.f;
    }
    for (int t = 0; t < TCH; t++){
      float dtv = sm[d*49 + t];
      float bb2 = dtv * sm[O_SXC + d*49 + t];
#pragma unroll
      for (int j = 0; j < SPB; j++){
        float a2 = __expf(dtv*Av[j]);
        Ar[j] *= a2;
        Br[j] = a2*Br[j] + bb2*sm[O_SB + (sh*SPB+j)*49 + t];
      }
    }
    const int o = chunk*CH + tid*SPB;
    if constexpr (SPB == 4){
      *reinterpret_cast<float4*>(&aggA[o]) = make_float4(Ar[0],Ar[1],Ar[2],Ar[3]);
      *reinterpret_cast<float4*>(&aggB[o]) = make_float4(Br[0],Br[1],Br[2],Br[3]);
    } else {
      *reinterpret_cast<float2*>(&aggA[o]) = make_float2(Ar[0],Ar[1]);
      *reinterpret_cast<float2*>(&aggB[o]) = make_float2(Br[0],Br[1]);
    }
  }
}

// ---------------- parallel scan over chunk aggregates -> carries ------------------
// 16 channels x 16 segments per 256-thread block; grid = CH/16 blocks.
template<int NCH>
__global__ __launch_bounds__(256) void k_carry(const float* __restrict__ aggA,
                        const float* __restrict__ aggB,
                        float* __restrict__ carry, int CH) {
  constexpr int SEG = NCH/16;         // 48 chunks per segment
  const int chl = threadIdx.x & 15;
  const int seg = threadIdx.x >> 4;
  const int ch  = blockIdx.x*16 + chl;
  const int c0  = seg*SEG;
  float a = 1.f, b = 0.f;
  for (int cb=c0; cb<c0+SEG; cb+=8){
    float av[8], bv[8];
#pragma unroll
    for (int k=0;k<8;k++){ av[k]=aggA[(cb+k)*CH+ch]; bv[k]=aggB[(cb+k)*CH+ch]; }
#pragma unroll
    for (int k=0;k<8;k++){ a = a*av[k]; b = av[k]*b + bv[k]; }
  }
  __shared__ float sa[16][17], sb[16][17];
  sa[seg][chl]=a; sb[seg][chl]=b;
  __syncthreads();
  if (threadIdx.x < 16){
    float pa=1.f, pb=0.f;
    for (int g=0; g<16; g++){
      float ca=sa[g][threadIdx.x], cb2=sb[g][threadIdx.x];
      sa[g][threadIdx.x]=pa; sb[g][threadIdx.x]=pb;
      float na = pa*ca;
      float nb = ca*pb + cb2;
      pa=na; pb=nb;
    }
  }
  __syncthreads();
  float h = sb[seg][chl];
  for (int cb=c0; cb<c0+SEG; cb+=8){
    float av[8], bv[8];
#pragma unroll
    for (int k=0;k<8;k++){ av[k]=aggA[(cb+k)*CH+ch]; bv[k]=aggB[(cb+k)*CH+ch]; }
#pragma unroll
    for (int k=0;k<8;k++){ carry[(cb+k)*CH+ch]=h; h = av[k]*h + bv[k]; }
  }
}

// =================================================================================
// k_back: fused pass2 scan + z-gate + out-proj + residual -> bf16 padded layout.
// =================================================================================
template<int DIM, int DI, int DTR, int RES>
__global__ __launch_bounds__(256) void k_back(
    const float* __restrict__ xcg, const float* __restrict__ zg,
    const float* __restrict__ dtpg, const float* __restrict__ Bg, const float* __restrict__ Cg,
    const float* __restrict__ dtw, const float* __restrict__ dtb,
    const float* __restrict__ Alog, const float* __restrict__ Dp,
    const float* __restrict__ carry,
    const float* __restrict__ ow,
    const float* __restrict__ r0src, const float* __restrict__ r1src,
    const float* __restrict__ bstats, const float* __restrict__ bg, const float* __restrict__ bbp,
    unsigned short* __restrict__ rp)
{
  constexpr int TCH = 48;
  constexpr int NSH = 256/DI;
  constexpr int SPB = 16/NSH;
  constexpr int ROWS = DTR + 32;
  constexpr int O_SXC = 0;               // DI*49
  constexpr int O_SDT = O_SXC + DI*49;   // DI*49
  constexpr int O_SB  = O_SDT + DI*49;   // 16*49
  constexpr int O_SC  = O_SB + 16*49;    // 16*49
  constexpr int O_SY  = O_SC + 16*49;    // DI*49
  constexpr int O_DTP = O_SY + DI*49;    // DTR*48
  constexpr int SMEM  = O_DTP + DTR*48 + 64;
  __shared__ float sm[SMEM];
  const int tid   = threadIdx.x;
  const int chunk = blockIdx.x;
  const int t0    = chunk*TCH;

  // ---- load xc / B / C / dtp (float4 global, scalar LDS scatter)
  for (int idx = tid; idx < DI*12; idx += 256){
    int d = idx / 12, q = idx - d*12;
    float4 v = *reinterpret_cast<const float4*>(xcg + d*L_TOT + t0 + q*4);
    sm[O_SXC + d*49 + q*4+0] = v.x; sm[O_SXC + d*49 + q*4+1] = v.y;
    sm[O_SXC + d*49 + q*4+2] = v.z; sm[O_SXC + d*49 + q*4+3] = v.w;
  }
  for (int idx = tid; idx < ROWS*12; idx += 256){
    int r = idx / 12, q = idx - r*12;
    const float* src; float* dst;
    if (r < DTR)        { src = dtpg + r*L_TOT + t0 + q*4;         dst = &sm[O_DTP + r*48 + q*4]; }
    else if (r < DTR+16){ src = Bg + (r-DTR)*L_TOT + t0 + q*4;     dst = &sm[O_SB + (r-DTR)*49 + q*4]; }
    else                { src = Cg + (r-DTR-16)*L_TOT + t0 + q*4;  dst = &sm[O_SC + (r-DTR-16)*49 + q*4]; }
    float4 v = *reinterpret_cast<const float4*>(src);
    dst[0] = v.x; dst[1] = v.y; dst[2] = v.z; dst[3] = v.w;
  }
  __syncthreads();
  // ---- dt = softplus(dtb + dtw*dtp)
  for (int idx = tid; idx < DI*48; idx += 256){
    int d = idx / 48, j = idx - d*48;
    float pre = dtb[d] + dtw[d*DTR]*sm[O_DTP + j];
    if (DTR > 1) pre += dtw[d*DTR + DTR-1]*sm[O_DTP + 48 + j];
    sm[O_SDT + d*49 + j] = fsoftplus(pre);
  }
  __syncthreads();

  // ---- pass2 scan: h update + y = sum_s h*C + xc*D -> SY
  {
    const int d  = tid / NSH;
    const int sh = tid - d*NSH;
    float Av[SPB], h[SPB];
#pragma unroll
    for (int j = 0; j < SPB; j++){
      Av[j] = -__expf(Alog[d*16 + sh*SPB + j]);
      h[j]  = carry[chunk*(DI*16) + tid*SPB + j];
    }
    const float Dv = Dp[d];
    for (int t = 0; t < TCH; t++){
      float dtv = sm[O_SDT + d*49 + t];
      float xcv = sm[O_SXC + d*49 + t];
      float bb2 = dtv*xcv;
      float p = 0.f;
#pragma unroll
      for (int j = 0; j < SPB; j++){
        float a2 = __expf(dtv*Av[j]);
        h[j] = a2*h[j] + bb2*sm[O_SB + (sh*SPB+j)*49 + t];
        p += h[j]*sm[O_SC + (sh*SPB+j)*49 + t];
      }
#pragma unroll
      for (int o = 1; o < NSH; o <<= 1) p += __shfl_xor(p, o);
      if (sh == 0) sm[O_SY + d*49 + t] = p + xcv*Dv;
    }
  }
  __syncthreads();
  // ---- gate: y *= silu(z)   (z streamed from global, never staged)
  for (int idx = tid; idx < DI*12; idx += 256){
    int d = idx / 12, q = idx - d*12;
    float4 zv = *reinterpret_cast<const float4*>(zg + d*L_TOT + t0 + q*4);
    sm[O_SY + d*49 + q*4+0] *= zv.x*fsigmoid(zv.x);
    sm[O_SY + d*49 + q*4+1] *= zv.y*fsigmoid(zv.y);
    sm[O_SY + d*49 + q*4+2] *= zv.z*fsigmoid(zv.z);
    sm[O_SY + d*49 + q*4+3] *= zv.w*fsigmoid(zv.w);
  }
  __syncthreads();

  // ---- out-proj + residual -> padded bf16 conv input
  {
    const int col = tid & 63;
    const int r0w = __builtin_amdgcn_readfirstlane(tid >> 6);
    constexpr int NO = DIM/4;
    float acc[NO];
#pragma unroll
    for (int rr = 0; rr < NO; rr++) acc[rr] = 0.f;
    for (int db = 0; db < DI; db += 16){
      float ycol[16];
#pragma unroll
      for (int k = 0; k < 16; k++) ycol[k] = sm[O_SY + (db+k)*49 + col];
#pragma unroll
      for (int rr = 0; rr < NO; rr++){
        int r = r0w + rr*4;
        float a2 = 0.f;
#pragma unroll
        for (int k = 0; k < 16; k++) a2 += ycol[k]*ow[r*DI + db + k];
        acc[rr] += a2;
      }
    }
    if (col < 48){
      const int t  = t0 + col;
      const int zz = chunk / 48, yy = chunk - zz*48;     // 48 cols = one (zz,yy) row
      const int pb = (zz+1)*2500 + (yy+1)*50 + (col+1);
#pragma unroll
      for (int rr = 0; rr < NO; rr++){
        int r = r0w + rr*4;
        float res;
        if (RES == 0){
          res = (r < 16) ? r0src[r*L_TOT + t] : r1src[(r-16)*L_TOT + t];
        } else {
          float bm = bstats[2*r]*(1.f/L_TOT);
          float bv = bstats[2*r+1]*(1.f/L_TOT) - bm*bm;
          res = (r0src[r*L_TOT + t] - bm)*rsqrtf(bv+BN_EPS)*bg[r] + bbp[r];
        }
        rp[r*PCH + pb] = f2bf(acc[rr] + res);
      }
    }
  }
}

// ---------------- conv3d via MFMA implicit GEMM + fused BN partial sums -----------
template<int IC>
__global__ __launch_bounds__(256) void k_conv_mfma(const unsigned short* __restrict__ bin,
                         const unsigned short* __restrict__ wA,
                         const float* __restrict__ bias, float* __restrict__ out,
                         float* __restrict__ stats) {
  constexpr int NKB = (IC==32) ? 27 : 14;
  __shared__ float sred[32];
  if (threadIdx.x < 32) sred[threadIdx.x] = 0.f;
  __syncthreads();
  const int lane = threadIdx.x & 63;
  const int n = lane & 15, quad = lane >> 4;
  const int tile = blockIdx.x*4 + (threadIdx.x >> 6);
  const int t = tile*16 + n;
  int zz = t / 2304;
  int r2 = t - zz*2304;
  int yy = r2 / 48;
  int xx = r2 - yy*48;
  int pb = (zz+1)*2500 + (yy+1)*50 + (xx+1);
  const unsigned short* bp[8];
#pragma unroll
  for (int j=0;j<8;j++){
    int e = quad*8 + j;
    int ic = (IC==32) ? e : (e & 15);
    bp[j] = bin + ic*PCH + pb;
  }
  const int rq = (IC==32) ? 0 : (quad >> 1);
  f32x4 acc = {0.f, 0.f, 0.f, 0.f};
#pragma unroll
  for (int kb=0; kb<NKB; kb++){
    bf16x8 af = *reinterpret_cast<const bf16x8*>(wA + (size_t)((kb*4+quad)*16 + n)*8);
    int off;
    if (IC==32) off = off3c(kb);
    else        off = rq ? off3c(2*kb+1) : off3c(2*kb);
    bf16x8 bf;
#pragma unroll
    for (int j=0;j<8;j++) bf[j] = (short)bp[j][off];
    acc = __builtin_amdgcn_mfma_f32_16x16x32_bf16(af, bf, acc, 0, 0, 0);
  }
  float vs[4];
#pragma unroll
  for (int reg=0; reg<4; reg++){
    int m = quad*4 + reg;
    float v = acc[reg] + bias[m];
    out[m*L_TOT + t] = v;
    vs[reg] = v;
  }
#pragma unroll
  for (int reg=0; reg<4; reg++){
    float a = vs[reg], b2 = vs[reg]*vs[reg];
#pragma unroll
    for (int o=1; o<16; o<<=1){ a += __shfl_xor(a,o); b2 += __shfl_xor(b2,o); }
    if (n == 0){
      atomicAdd(&sred[quad*4+reg], a);
      atomicAdd(&sred[16 + quad*4+reg], b2);
    }
  }
  __syncthreads();
  if (threadIdx.x < 16){
    atomicAdd(&stats[2*threadIdx.x],   sred[threadIdx.x]);
    atomicAdd(&stats[2*threadIdx.x+1], sred[16+threadIdx.x]);
  }
}

// ---------------- BN normalize, float4 --------------------------------------------
__global__ void k_bn_norm4(const float* __restrict__ raw, const float* __restrict__ stats,
                           const float* __restrict__ g, const float* __restrict__ b,
                           float* __restrict__ out) {
  int i = blockIdx.x*256 + threadIdx.x;         // over 16*L_TOT/4
  int c = i / (L_TOT/4);
  int tq = i - c*(L_TOT/4);
  float m = stats[2*c]*(1.f/L_TOT);
  float v = stats[2*c+1]*(1.f/L_TOT) - m*m;
  float sc = rsqrtf(v+BN_EPS)*g[c];
  float bs = b[c] - m*sc;
  float4 x = *reinterpret_cast<const float4*>(raw + c*L_TOT + tq*4);
  float4 o = make_float4(x.x*sc+bs, x.y*sc+bs, x.z*sc+bs, x.w*sc+bs);
  *reinterpret_cast<float4*>(out + c*L_TOT + tq*4) = o;
}

// =================================================================================
extern "C" void kernel_launch(void* const* d_in, const int* in_sizes, int n_in,
                              void* d_out, int out_size, void* d_ws, size_t ws_size,
                              hipStream_t stream) {
  const float* l        = (const float*)d_in[0];
  const float* s        = (const float*)d_in[1];
  const float* m1_ln_w  = (const float*)d_in[2];
  const float* m1_ln_b  = (const float*)d_in[3];
  const float* m1_in_w  = (const float*)d_in[4];
  const float* m1_cw    = (const float*)d_in[5];
  const float* m1_cb    = (const float*)d_in[6];
  const float* m1_xp_w  = (const float*)d_in[7];
  const float* m1_dt_w  = (const float*)d_in[8];
  const float* m1_dt_b  = (const float*)d_in[9];
  const float* m1_Alog  = (const float*)d_in[10];
  const float* m1_D     = (const float*)d_in[11];
  const float* m1_out_w = (const float*)d_in[12];
  const float* m2_ln_w  = (const float*)d_in[13];
  const float* m2_ln_b  = (const float*)d_in[14];
  const float* m2_in_w  = (const float*)d_in[15];
  const float* m2_cw    = (const float*)d_in[16];
  const float* m2_cb    = (const float*)d_in[17];
  const float* m2_xp_w  = (const float*)d_in[18];
  const float* m2_dt_w  = (const float*)d_in[19];
  const float* m2_dt_b  = (const float*)d_in[20];
  const float* m2_Alog  = (const float*)d_in[21];
  const float* m2_D     = (const float*)d_in[22];
  const float* m2_out_w = (const float*)d_in[23];
  const float* c1_w     = (const float*)d_in[24];
  const float* c1_b     = (const float*)d_in[25];
  const float* bn1_g    = (const float*)d_in[26];
  const float* bn1_b    = (const float*)d_in[27];
  const float* c2_w     = (const float*)d_in[28];
  const float* c2_b     = (const float*)d_in[29];
  const float* bn2_g    = (const float*)d_in[30];
  const float* bn2_b    = (const float*)d_in[31];

  float* ws = (float*)d_ws;
  const size_t L = L_TOT;
  float* xc1      = ws;               // 64L
  float* z1       = ws + 64*L;        // 64L
  float* B1       = ws + 128*L;       // 16L   (reused by stage 2)
  float* C1       = ws + 144*L;       // 16L   (reused by stage 2)
  float* dtp1     = ws + 160*L;       // 2L    (reused by stage 2)
  float* conv1raw = ws + 162*L;       // 16L
  float* xc2      = ws + 178*L;       // 32L
  float* z2       = ws + 210*L;       // 32L
  float* conv2raw = ws + 242*L;       // 16L
  float* aggA     = ws + 258*L;       // 786432
  float* aggB     = aggA + 786432;
  float* carry    = aggB + 786432;    // ends at 322L
  float* stats1   = ws + 322*L;       // 32
  float* stats2   = stats1 + 32;      // 32
  unsigned short* bfin = (unsigned short*)(ws + 323*L);   // 32ch * PCH bf16
  unsigned short* wA1  = (unsigned short*)(ws + 343*L);   // 13824
  unsigned short* wA2  = wA1 + 13824;                     // 7168

  // ================= stage 1: mamba(dim=32, di=64) + conv1 + bn1(stats) ==========
  // k_front<...,SETUP=true> also performs the old k_setup work (weight pack, bfin
  // halo zero, stats zero) - all consumed only by later kernels in stream order.
  k_front<32,64,2,false,true><<<768,256,0,stream>>>(l, s, stats1, bn1_g, bn1_b,
      m1_ln_w, m1_ln_b, m1_in_w, m1_cw, m1_cb, m1_xp_w, m1_dt_w, m1_dt_b, m1_Alog,
      xc1, z1, dtp1, B1, C1, aggA, aggB,
      c1_w, wA1, c2_w, wA2, stats1, (float*)bfin);
  k_carry<768><<<64,256,0,stream>>>(aggA, aggB, carry, 1024);
  k_back<32,64,2,0><<<768,256,0,stream>>>(xc1, z1, dtp1, B1, C1,
      m1_dt_w, m1_dt_b, m1_Alog, m1_D, carry, m1_out_w, l, s,
      stats1, bn1_g, bn1_b, bfin);
  k_conv_mfma<32><<<576,256,0,stream>>>(bfin, wA1, c1_b, conv1raw, stats1);

  // ================= stage 2: mamba(dim=16, di=32) + conv2 + bn2 =================
  k_front<16,32,1,true,false><<<768,256,0,stream>>>(conv1raw, conv1raw, stats1, bn1_g, bn1_b,
      m2_ln_w, m2_ln_b, m2_in_w, m2_cw, m2_cb, m2_xp_w, m2_dt_w, m2_dt_b, m2_Alog,
      xc2, z2, dtp1, B1, C1, aggA, aggB,
      nullptr, nullptr, nullptr, nullptr, nullptr, nullptr);
  k_carry<768><<<32,256,0,stream>>>(aggA, aggB, carry, 512);
  k_back<16,32,1,1><<<768,256,0,stream>>>(xc2, z2, dtp1, B1, C1,
      m2_dt_w, m2_dt_b, m2_Alog, m2_D, carry, m2_out_w, conv1raw, conv1raw,
      stats1, bn1_g, bn1_b, bfin);
  k_conv_mfma<16><<<576,256,0,stream>>>(bfin, wA2, c2_b, conv2raw, stats2);
  k_bn_norm4<<<576,256,0,stream>>>(conv2raw, stats2, bn2_g, bn2_b, (float*)d_out);
}

// Round 13
// 270.818 us; speedup vs baseline: 1.1953x; 1.0452x over previous
//
#include <hip/hip_runtime.h>
#include <math.h>

#define L_TOT 36864
#define BN_EPS 1e-5f
#define PCH 45000   // padded channel stride: 18*50*50

typedef __attribute__((ext_vector_type(8))) short bf16x8;
typedef __attribute__((ext_vector_type(4))) float f32x4;

__device__ __forceinline__ float fsigmoid(float x){ return 1.f/(1.f+__expf(-x)); }
__device__ __forceinline__ float fsoftplus(float x){
  float e = __expf(x);
  return (x>20.f)? x : __logf(1.f+e);
}
__device__ __forceinline__ unsigned short f2bf(float x){
  union { float f; unsigned u; } cv; cv.f = x;
  unsigned r = (cv.u + 0x7FFFu + ((cv.u>>16)&1u)) >> 16;
  return (unsigned short)r;
}
__host__ __device__ constexpr int off3c(int r){
  return (r>=27) ? 0 : ((r/9)-1)*2500 + (((r%9)/3)-1)*50 + ((r%3)-1);
}

// =================================================================================
// k_front: fused LN (+BN-on-read) + MFMA in-proj + dwconv/SiLU + MFMA x-proj +
//          dt + pass1 chunk aggregates.  One block = one chunk of 48 timesteps.
// All matmul-shaped phases run on matrix cores with the proven fragment layout
// (A: row=ln&15,k=(ln>>4)*8+j; B: col=ln&15,same k; D: col=ln&15,row=(ln>>4)*4+r).
// x-proj A-frags reuse the dead in-proj frag region; dwconv emits a bf16 xc panel
// as a side product. Region0 (DI*64) time-aliased: xs(+halo) -> dt (stride 49).
// SETUP=true (stage 1): folds conv-weight pack / bfin halo zero / stats zero.
// =================================================================================
template<int DIM, int DI, int DTR, bool DOBN, bool SETUP>
__global__ __launch_bounds__(256) void k_front(
    const float* __restrict__ x0, const float* __restrict__ x1,
    const float* __restrict__ bstats, const float* __restrict__ bg, const float* __restrict__ bbp,
    const float* __restrict__ lnw, const float* __restrict__ lnb,
    const float* __restrict__ inw,
    const float* __restrict__ cw, const float* __restrict__ cb,
    const float* __restrict__ xpw,
    const float* __restrict__ dtw, const float* __restrict__ dtb,
    const float* __restrict__ Alog,
    float* __restrict__ xcg, float* __restrict__ zg,
    float* __restrict__ dtpg, float* __restrict__ Bg, float* __restrict__ Cg,
    float* __restrict__ aggA, float* __restrict__ aggB,
    const float* __restrict__ cvw1, unsigned short* __restrict__ wA1,
    const float* __restrict__ cvw2, unsigned short* __restrict__ wA2,
    float* __restrict__ stats, float* __restrict__ bfz)
{
  constexpr int TCH  = 48;
  constexpr int ROWS = DTR + 32;
  constexpr int NSH  = 256/DI;        // threads per d-channel in scan
  constexpr int SPB  = 16/NSH;        // states per thread
  constexpr int CH   = DI*16;
  constexpr int NRT  = (2*DI)/16;     // in-proj row-tiles (8 / 4)
  constexpr int NKC  = DI/32;         // K-chunks for x-proj (K=DI: 2 / 1)
  constexpr int NRX  = 3;             // x-proj row-tiles (ceil(ROWS/16))
  constexpr int R0SZ = DI*64;         // region0: xs+halo (DI*64) / dt (DI*49)
  constexpr int O_SXC = R0SZ;         // DI*49  (aliases bf16 xn panel pre-P3)
  constexpr int O_SB  = O_SXC + DI*49;// 16*49
  constexpr int O_SC  = O_SB + 16*49; // 16*49
  constexpr int O_DTP = O_SC + 16*49; // DTR*48
  constexpr int O_WA  = O_DTP + DTR*48;     // in-proj A-frags, reused for xpw frags
  constexpr int OWASZ = ((NRT > NRX*NKC) ? NRT : NRX*NKC)*256;
  constexpr int O_XCP = O_WA + OWASZ;       // bf16 xc panel: 24*DI floats
  constexpr int SMEM  = O_XCP + 24*DI + 16;
  __shared__ float sm[SMEM];

  const int tid   = threadIdx.x;
  const int chunk = blockIdx.x;
  const int t0    = chunk*TCH;

  // ---- folded setup (stage 1): outputs consumed only by later kernels ----------
  if constexpr (SETUP){
    for (int idx = blockIdx.x*256 + tid; idx < 16*PCH; idx += 768*256)
      bfz[idx] = 0.f;                          // zero bf16 halo buffer (32-bit words)
    const int b = blockIdx.x;
    if (b < 4){
      int k = b*256 + tid;
      if (k < 864){
        int ic = k & 31, r = k >> 5;
        for (int m=0;m<16;m++){
          float v = (r < 27) ? cvw1[m*32*27 + ic*27 + r] : 0.f;
          wA1[(((k>>3)*16) + m)*8 + (k&7)] = f2bf(v);
        }
      }
    } else if (b < 6){
      int k = (b-4)*256 + tid;
      if (k < 448){
        int ic = k & 15, r = k >> 4;
        for (int m=0;m<16;m++){
          float v = (r < 27) ? cvw2[m*16*27 + ic*27 + r] : 0.f;
          wA2[(((k>>3)*16) + m)*8 + (k&7)] = f2bf(v);
        }
      }
    } else if (b == 6){
      if (tid < 64) stats[tid] = 0.f;
    }
  }

  const int i   = tid & 63;
  const int r0w = __builtin_amdgcn_readfirstlane(tid >> 6);

  // ---- P012: pack inw A-frags -> LDS; x -> regs (+BN) -> LN -> bf16 B-panel ----
  {
    unsigned short* winAl = (unsigned short*)&sm[O_WA];
    unsigned short* xnl   = (unsigned short*)&sm[O_SXC];   // 64 cols x 32 k (bf16)
    for (int sidx = tid; sidx < NRT*64; sidx += 256){
      int ln  = sidx & 63;
      int row = (sidx >> 6)*16 + (ln & 15);
      int k0  = (ln >> 4)*8;
      unsigned short* wp = winAl + sidx*8;
#pragma unroll
      for (int j = 0; j < 8; j++){
        int k = k0 + j;
        wp[j] = (k < DIM) ? f2bf(inw[row*DIM + k]) : (unsigned short)0;
      }
    }
    float xn[DIM];
    const int t = t0 - 3 + i;
    const bool valid = (i < 51 && t >= 0);
#pragma unroll
    for (int c = 0; c < DIM; c++){
      float v = 0.f;
      if (valid){
        if constexpr (DOBN){
          float raw = x0[c*L_TOT + t];
          float bm = bstats[2*c]*(1.f/L_TOT);
          float bv = bstats[2*c+1]*(1.f/L_TOT) - bm*bm;
          v = (raw - bm)*rsqrtf(bv+BN_EPS)*bg[c] + bbp[c];
        } else {
          v = (c < 16) ? x0[c*L_TOT + t] : x1[(c-16)*L_TOT + t];
        }
      }
      xn[c] = v;
    }
    float s = 0.f, s2 = 0.f;
#pragma unroll
    for (int c = 0; c < DIM; c++){ s += xn[c]; s2 += xn[c]*xn[c]; }
    float m  = s*(1.f/DIM);
    float var = s2*(1.f/DIM) - m*m;
    float rs = rsqrtf(var + BN_EPS);
    unsigned short* xr = xnl + i*32;
#pragma unroll
    for (int c = 0; c < DIM; c++) xr[c] = f2bf((xn[c]-m)*rs*lnw[c] + lnb[c]);
    if constexpr (DIM < 32){
#pragma unroll
      for (int c = DIM; c < 32; c++) xr[c] = 0;
    }
  }
  __syncthreads();

  // ---- P2-MFMA: in-proj D = inw x xn.  wave = 16-col tile, NRT row-tiles -------
  {
    const unsigned short* winAl = (const unsigned short*)&sm[O_WA];
    const unsigned short* xnl   = (const unsigned short*)&sm[O_SXC];
    const int ln  = tid & 63;
    const int wv  = tid >> 6;              // col-tile
    const int col = wv*16 + (ln & 15);
    bf16x8 bfr = *reinterpret_cast<const bf16x8*>(xnl + (size_t)col*32 + (ln>>4)*8);
    f32x4 zero = {0.f,0.f,0.f,0.f};
#pragma unroll
    for (int rt = 0; rt < NRT; rt++){
      bf16x8 af = *reinterpret_cast<const bf16x8*>(winAl + (size_t)(rt*64 + ln)*8);
      f32x4 dd = __builtin_amdgcn_mfma_f32_16x16x32_bf16(af, bfr, zero, 0, 0, 0);
#pragma unroll
      for (int r = 0; r < 4; r++){
        int row = rt*16 + (ln>>4)*4 + r;
        if (row < DI){
          if (col < 51) sm[row*64 + col] = (t0 == 0 && col < 3) ? 0.f : dd[r];
        } else {
          if (col >= 3 && col < 51) zg[(row-DI)*L_TOT + t0 + col - 3] = dd[r];
        }
      }
    }
  }
  __syncthreads();

  // ---- P3: dwconv (kw=4) + SiLU -> SXC f32 + bf16 xc panel; pack xpw A-frags ---
  {
    unsigned short* xcp = (unsigned short*)&sm[O_XCP];
    for (int idx = tid; idx < DI*48; idx += 256){
      int d = idx / 48, j = idx - d*48;
      const float* xr = &sm[d*64 + j];     // xr[k] = xs[t-3+k]
      float acc = cb[d] + cw[d*4+0]*xr[0] + cw[d*4+1]*xr[1]
                        + cw[d*4+2]*xr[2] + cw[d*4+3]*xr[3];
      float v = acc * fsigmoid(acc);
      sm[O_SXC + d*49 + j] = v;
      xcp[j*DI + d] = f2bf(v);
    }
    unsigned short* wfr = (unsigned short*)&sm[O_WA];   // in-proj frags dead
    for (int sidx = tid; sidx < NRX*NKC*64; sidx += 256){
      int ln = sidx & 63;
      int fi = sidx >> 6;
      int rt = fi / NKC, kc = fi - rt*NKC;
      int row = rt*16 + (ln & 15);
      int k0  = kc*32 + (ln>>4)*8;
      unsigned short* wp = wfr + sidx*8;
#pragma unroll
      for (int j = 0; j < 8; j++)
        wp[j] = (row < ROWS) ? f2bf(xpw[row*DI + k0 + j]) : (unsigned short)0;
    }
  }
  __syncthreads();

  // ---- P4-MFMA: x-proj D = xpw x xc -> dtp | B | C
  {
    const unsigned short* wfr = (const unsigned short*)&sm[O_WA];
    const unsigned short* xcp = (const unsigned short*)&sm[O_XCP];
    const int ln = tid & 63;
    const int wv = tid >> 6;
    for (int job = wv; job < NRX*3; job += 4){
      int rt = job / 3, ct = job - rt*3;
      int col = ct*16 + (ln & 15);
      f32x4 acc = {0.f,0.f,0.f,0.f};
#pragma unroll
      for (int kc = 0; kc < NKC; kc++){
        bf16x8 af  = *reinterpret_cast<const bf16x8*>(wfr + (size_t)((rt*NKC+kc)*64 + ln)*8);
        bf16x8 bfr = *reinterpret_cast<const bf16x8*>(xcp + (size_t)col*DI + kc*32 + (ln>>4)*8);
        acc = __builtin_amdgcn_mfma_f32_16x16x32_bf16(af, bfr, acc, 0, 0, 0);
      }
#pragma unroll
      for (int r = 0; r < 4; r++){
        int row = rt*16 + (ln>>4)*4 + r;
        if (row < DTR)           sm[O_DTP + row*48 + col] = acc[r];
        else if (row < DTR+16)   sm[O_SB + (row-DTR)*49 + col] = acc[r];
        else if (row < ROWS)     sm[O_SC + (row-DTR-16)*49 + col] = acc[r];
      }
    }
  }
  __syncthreads();

  // ---- P5: dt = softplus(dtb + dtw*dtp) -> region0 (xs dead)
  for (int idx = tid; idx < DI*48; idx += 256){
    int d = idx / 48, j = idx - d*48;
    float pre = dtb[d] + dtw[d*DTR]*sm[O_DTP + j];
    if (DTR > 1) pre += dtw[d*DTR + DTR-1]*sm[O_DTP + (DTR-1)*48 + j];
    sm[d*49 + j] = fsoftplus(pre);
  }
  __syncthreads();

  // ---- P6: spill xc/dtp/B/C to global, all float4 (stores fly during pass1)
  for (int idx = tid; idx < DI*12; idx += 256){
    int d = idx / 12, q = idx - d*12;
    float4 v = make_float4(sm[O_SXC + d*49 + q*4+0], sm[O_SXC + d*49 + q*4+1],
                           sm[O_SXC + d*49 + q*4+2], sm[O_SXC + d*49 + q*4+3]);
    *reinterpret_cast<float4*>(xcg + d*L_TOT + t0 + q*4) = v;
  }
  for (int idx = tid; idx < ROWS*12; idx += 256){
    int r = idx / 12, q = idx - r*12;
    const float* src; float* dst;
    if (r < DTR)        { src = &sm[O_DTP + r*48 + q*4];          dst = dtpg + r*L_TOT + t0 + q*4; }
    else if (r < DTR+16){ src = &sm[O_SB + (r-DTR)*49 + q*4];     dst = Bg + (r-DTR)*L_TOT + t0 + q*4; }
    else                { src = &sm[O_SC + (r-DTR-16)*49 + q*4];  dst = Cg + (r-DTR-16)*L_TOT + t0 + q*4; }
    *reinterpret_cast<float4*>(dst) = make_float4(src[0], src[1], src[2], src[3]);
  }

  // ---- P7: pass1 scan -> per-chunk (A,B) aggregates
  {
    const int d  = tid / NSH;
    const int sh = tid - d*NSH;
    float Av[SPB], Ar[SPB], Br[SPB];
#pragma unroll
    for (int j = 0; j < SPB; j++){
      Av[j] = -__expf(Alog[d*16 + sh*SPB + j]);
      Ar[j] = 1.f; Br[j] = 0.f;
    }
    for (int t = 0; t < TCH; t++){
      float dtv = sm[d*49 + t];
      float bb2 = dtv * sm[O_SXC + d*49 + t];
#pragma unroll
      for (int j = 0; j < SPB; j++){
        float a2 = __expf(dtv*Av[j]);
        Ar[j] *= a2;
        Br[j] = a2*Br[j] + bb2*sm[O_SB + (sh*SPB+j)*49 + t];
      }
    }
    const int o = chunk*CH + tid*SPB;
    if constexpr (SPB == 4){
      *reinterpret_cast<float4*>(&aggA[o]) = make_float4(Ar[0],Ar[1],Ar[2],Ar[3]);
      *reinterpret_cast<float4*>(&aggB[o]) = make_float4(Br[0],Br[1],Br[2],Br[3]);
    } else {
      *reinterpret_cast<float2*>(&aggA[o]) = make_float2(Ar[0],Ar[1]);
      *reinterpret_cast<float2*>(&aggB[o]) = make_float2(Br[0],Br[1]);
    }
  }
}

// ---------------- parallel scan over chunk aggregates -> carries ------------------
// 16 channels x 16 segments per 256-thread block; grid = CH/16 blocks.
template<int NCH>
__global__ __launch_bounds__(256) void k_carry(const float* __restrict__ aggA,
                        const float* __restrict__ aggB,
                        float* __restrict__ carry, int CH) {
  constexpr int SEG = NCH/16;         // 48 chunks per segment
  const int chl = threadIdx.x & 15;
  const int seg = threadIdx.x >> 4;
  const int ch  = blockIdx.x*16 + chl;
  const int c0  = seg*SEG;
  float a = 1.f, b = 0.f;
  for (int cb=c0; cb<c0+SEG; cb+=8){
    float av[8], bv[8];
#pragma unroll
    for (int k=0;k<8;k++){ av[k]=aggA[(cb+k)*CH+ch]; bv[k]=aggB[(cb+k)*CH+ch]; }
#pragma unroll
    for (int k=0;k<8;k++){ a = a*av[k]; b = av[k]*b + bv[k]; }
  }
  __shared__ float sa[16][17], sb[16][17];
  sa[seg][chl]=a; sb[seg][chl]=b;
  __syncthreads();
  if (threadIdx.x < 16){
    float pa=1.f, pb=0.f;
    for (int g=0; g<16; g++){
      float ca=sa[g][threadIdx.x], cb2=sb[g][threadIdx.x];
      sa[g][threadIdx.x]=pa; sb[g][threadIdx.x]=pb;
      float na = pa*ca;
      float nb = ca*pb + cb2;
      pa=na; pb=nb;
    }
  }
  __syncthreads();
  float h = sb[seg][chl];
  for (int cb=c0; cb<c0+SEG; cb+=8){
    float av[8], bv[8];
#pragma unroll
    for (int k=0;k<8;k++){ av[k]=aggA[(cb+k)*CH+ch]; bv[k]=aggB[(cb+k)*CH+ch]; }
#pragma unroll
    for (int k=0;k<8;k++){ carry[(cb+k)*CH+ch]=h; h = av[k]*h + bv[k]; }
  }
}

// =================================================================================
// k_back: fused pass2 scan + z-gate + MFMA out-proj + residual -> bf16 padded.
// Gate emits a bf16 y panel over the dead dt region; ow A-frags pack over the
// dead xc region. Out-proj D-tiles add residual and store directly.
// =================================================================================
template<int DIM, int DI, int DTR, int RES>
__global__ __launch_bounds__(256) void k_back(
    const float* __restrict__ xcg, const float* __restrict__ zg,
    const float* __restrict__ dtpg, const float* __restrict__ Bg, const float* __restrict__ Cg,
    const float* __restrict__ dtw, const float* __restrict__ dtb,
    const float* __restrict__ Alog, const float* __restrict__ Dp,
    const float* __restrict__ carry,
    const float* __restrict__ ow,
    const float* __restrict__ r0src, const float* __restrict__ r1src,
    const float* __restrict__ bstats, const float* __restrict__ bg, const float* __restrict__ bbp,
    unsigned short* __restrict__ rp)
{
  constexpr int TCH = 48;
  constexpr int NSH = 256/DI;
  constexpr int SPB = 16/NSH;
  constexpr int ROWS = DTR + 32;
  constexpr int NRO = DIM/16;            // out-proj row-tiles (2 / 1)
  constexpr int NKC = DI/32;             // K-chunks (2 / 1)
  constexpr int O_SXC = 0;               // DI*49  (later: ow A-frags)
  constexpr int O_SDT = O_SXC + DI*49;   // DI*49  (later: bf16 y panel)
  constexpr int O_SB  = O_SDT + DI*49;   // 16*49
  constexpr int O_SC  = O_SB + 16*49;    // 16*49
  constexpr int O_SY  = O_SC + 16*49;    // DI*49
  constexpr int O_DTP = O_SY + DI*49;    // DTR*48
  constexpr int SMEM  = O_DTP + DTR*48 + 64;
  __shared__ float sm[SMEM];
  const int tid   = threadIdx.x;
  const int chunk = blockIdx.x;
  const int t0    = chunk*TCH;

  // ---- load xc / B / C / dtp (float4 global, scalar LDS scatter)
  for (int idx = tid; idx < DI*12; idx += 256){
    int d = idx / 12, q = idx - d*12;
    float4 v = *reinterpret_cast<const float4*>(xcg + d*L_TOT + t0 + q*4);
    sm[O_SXC + d*49 + q*4+0] = v.x; sm[O_SXC + d*49 + q*4+1] = v.y;
    sm[O_SXC + d*49 + q*4+2] = v.z; sm[O_SXC + d*49 + q*4+3] = v.w;
  }
  for (int idx = tid; idx < ROWS*12; idx += 256){
    int r = idx / 12, q = idx - r*12;
    const float* src; float* dst;
    if (r < DTR)        { src = dtpg + r*L_TOT + t0 + q*4;         dst = &sm[O_DTP + r*48 + q*4]; }
    else if (r < DTR+16){ src = Bg + (r-DTR)*L_TOT + t0 + q*4;     dst = &sm[O_SB + (r-DTR)*49 + q*4]; }
    else                { src = Cg + (r-DTR-16)*L_TOT + t0 + q*4;  dst = &sm[O_SC + (r-DTR-16)*49 + q*4]; }
    float4 v = *reinterpret_cast<const float4*>(src);
    dst[0] = v.x; dst[1] = v.y; dst[2] = v.z; dst[3] = v.w;
  }
  __syncthreads();
  // ---- dt = softplus(dtb + dtw*dtp)
  for (int idx = tid; idx < DI*48; idx += 256){
    int d = idx / 48, j = idx - d*48;
    float pre = dtb[d] + dtw[d*DTR]*sm[O_DTP + j];
    if (DTR > 1) pre += dtw[d*DTR + DTR-1]*sm[O_DTP + 48 + j];
    sm[O_SDT + d*49 + j] = fsoftplus(pre);
  }
  __syncthreads();

  // ---- pass2 scan: h update + y = sum_s h*C + xc*D -> SY
  {
    const int d  = tid / NSH;
    const int sh = tid - d*NSH;
    float Av[SPB], h[SPB];
#pragma unroll
    for (int j = 0; j < SPB; j++){
      Av[j] = -__expf(Alog[d*16 + sh*SPB + j]);
      h[j]  = carry[chunk*(DI*16) + tid*SPB + j];
    }
    const float Dv = Dp[d];
    for (int t = 0; t < TCH; t++){
      float dtv = sm[O_SDT + d*49 + t];
      float xcv = sm[O_SXC + d*49 + t];
      float bb2 = dtv*xcv;
      float p = 0.f;
#pragma unroll
      for (int j = 0; j < SPB; j++){
        float a2 = __expf(dtv*Av[j]);
        h[j] = a2*h[j] + bb2*sm[O_SB + (sh*SPB+j)*49 + t];
        p += h[j]*sm[O_SC + (sh*SPB+j)*49 + t];
      }
#pragma unroll
      for (int o = 1; o < NSH; o <<= 1) p += __shfl_xor(p, o);
      if (sh == 0) sm[O_SY + d*49 + t] = p + xcv*Dv;
    }
  }
  __syncthreads();

  // ---- gate -> bf16 y panel (over dead dt); pack ow A-frags (over dead xc) -----
  {
    unsigned short* yp  = (unsigned short*)&sm[O_SDT];
    unsigned short* wfr = (unsigned short*)&sm[O_SXC];
    for (int sidx = tid; sidx < NRO*NKC*64; sidx += 256){
      int ln = sidx & 63;
      int fi = sidx >> 6;
      int rt = fi / NKC, kc = fi - rt*NKC;
      int row = rt*16 + (ln & 15);
      int k0  = kc*32 + (ln>>4)*8;
      unsigned short* wp = wfr + sidx*8;
#pragma unroll
      for (int j = 0; j < 8; j++) wp[j] = f2bf(ow[row*DI + k0 + j]);
    }
    for (int idx = tid; idx < DI*12; idx += 256){
      int d = idx / 12, q = idx - d*12;
      float4 zv = *reinterpret_cast<const float4*>(zg + d*L_TOT + t0 + q*4);
      float y0 = sm[O_SY + d*49 + q*4+0];
      float y1 = sm[O_SY + d*49 + q*4+1];
      float y2 = sm[O_SY + d*49 + q*4+2];
      float y3 = sm[O_SY + d*49 + q*4+3];
      yp[(q*4+0)*DI + d] = f2bf(y0 * zv.x*fsigmoid(zv.x));
      yp[(q*4+1)*DI + d] = f2bf(y1 * zv.y*fsigmoid(zv.y));
      yp[(q*4+2)*DI + d] = f2bf(y2 * zv.z*fsigmoid(zv.z));
      yp[(q*4+3)*DI + d] = f2bf(y3 * zv.w*fsigmoid(zv.w));
    }
  }
  __syncthreads();

  // ---- out-proj via MFMA + residual -> padded bf16 conv input ------------------
  {
    const unsigned short* yp  = (const unsigned short*)&sm[O_SDT];
    const unsigned short* wfr = (const unsigned short*)&sm[O_SXC];
    const int ln = tid & 63;
    const int wv = tid >> 6;
    const int zz = chunk / 48, yy = chunk - zz*48;     // 48 cols = one (zz,yy) row
    for (int job = wv; job < NRO*3; job += 4){
      int rt = job / 3, ct = job - rt*3;
      int col = ct*16 + (ln & 15);
      f32x4 acc = {0.f,0.f,0.f,0.f};
#pragma unroll
      for (int kc = 0; kc < NKC; kc++){
        bf16x8 af  = *reinterpret_cast<const bf16x8*>(wfr + (size_t)((rt*NKC+kc)*64 + ln)*8);
        bf16x8 bfr = *reinterpret_cast<const bf16x8*>(yp + (size_t)col*DI + kc*32 + (ln>>4)*8);
        acc = __builtin_amdgcn_mfma_f32_16x16x32_bf16(af, bfr, acc, 0, 0, 0);
      }
      const int t  = t0 + col;
      const int pb = (zz+1)*2500 + (yy+1)*50 + (col+1);
#pragma unroll
      for (int r = 0; r < 4; r++){
        int row = rt*16 + (ln>>4)*4 + r;
        float res;
        if (RES == 0){
          res = (row < 16) ? r0src[row*L_TOT + t] : r1src[(row-16)*L_TOT + t];
        } else {
          float bm = bstats[2*row]*(1.f/L_TOT);
          float bv = bstats[2*row+1]*(1.f/L_TOT) - bm*bm;
          res = (r0src[row*L_TOT + t] - bm)*rsqrtf(bv+BN_EPS)*bg[row] + bbp[row];
        }
        rp[row*PCH + pb] = f2bf(acc[r] + res);
      }
    }
  }
}

// ---------------- conv3d via MFMA implicit GEMM + fused BN partial sums -----------
template<int IC>
__global__ __launch_bounds__(256) void k_conv_mfma(const unsigned short* __restrict__ bin,
                         const unsigned short* __restrict__ wA,
                         const float* __restrict__ bias, float* __restrict__ out,
                         float* __restrict__ stats) {
  constexpr int NKB = (IC==32) ? 27 : 14;
  __shared__ float sred[32];
  if (threadIdx.x < 32) sred[threadIdx.x] = 0.f;
  __syncthreads();
  const int lane = threadIdx.x & 63;
  const int n = lane & 15, quad = lane >> 4;
  const int tile = blockIdx.x*4 + (threadIdx.x >> 6);
  const int t = tile*16 + n;
  int zz = t / 2304;
  int r2 = t - zz*2304;
  int yy = r2 / 48;
  int xx = r2 - yy*48;
  int pb = (zz+1)*2500 + (yy+1)*50 + (xx+1);
  const unsigned short* bp[8];
#pragma unroll
  for (int j=0;j<8;j++){
    int e = quad*8 + j;
    int ic = (IC==32) ? e : (e & 15);
    bp[j] = bin + ic*PCH + pb;
  }
  const int rq = (IC==32) ? 0 : (quad >> 1);
  f32x4 acc = {0.f, 0.f, 0.f, 0.f};
#pragma unroll
  for (int kb=0; kb<NKB; kb++){
    bf16x8 af = *reinterpret_cast<const bf16x8*>(wA + (size_t)((kb*4+quad)*16 + n)*8);
    int off;
    if (IC==32) off = off3c(kb);
    else        off = rq ? off3c(2*kb+1) : off3c(2*kb);
    bf16x8 bf;
#pragma unroll
    for (int j=0;j<8;j++) bf[j] = (short)bp[j][off];
    acc = __builtin_amdgcn_mfma_f32_16x16x32_bf16(af, bf, acc, 0, 0, 0);
  }
  float vs[4];
#pragma unroll
  for (int reg=0; reg<4; reg++){
    int m = quad*4 + reg;
    float v = acc[reg] + bias[m];
    out[m*L_TOT + t] = v;
    vs[reg] = v;
  }
#pragma unroll
  for (int reg=0; reg<4; reg++){
    float a = vs[reg], b2 = vs[reg]*vs[reg];
#pragma unroll
    for (int o=1; o<16; o<<=1){ a += __shfl_xor(a,o); b2 += __shfl_xor(b2,o); }
    if (n == 0){
      atomicAdd(&sred[quad*4+reg], a);
      atomicAdd(&sred[16 + quad*4+reg], b2);
    }
  }
  __syncthreads();
  if (threadIdx.x < 16){
    atomicAdd(&stats[2*threadIdx.x],   sred[threadIdx.x]);
    atomicAdd(&stats[2*threadIdx.x+1], sred[16+threadIdx.x]);
  }
}

// ---------------- BN normalize, float4 --------------------------------------------
__global__ void k_bn_norm4(const float* __restrict__ raw, const float* __restrict__ stats,
                           const float* __restrict__ g, const float* __restrict__ b,
                           float* __restrict__ out) {
  int i = blockIdx.x*256 + threadIdx.x;         // over 16*L_TOT/4
  int c = i / (L_TOT/4);
  int tq = i - c*(L_TOT/4);
  float m = stats[2*c]*(1.f/L_TOT);
  float v = stats[2*c+1]*(1.f/L_TOT) - m*m;
  float sc = rsqrtf(v+BN_EPS)*g[c];
  float bs = b[c] - m*sc;
  float4 x = *reinterpret_cast<const float4*>(raw + c*L_TOT + tq*4);
  float4 o = make_float4(x.x*sc+bs, x.y*sc+bs, x.z*sc+bs, x.w*sc+bs);
  *reinterpret_cast<float4*>(out + c*L_TOT + tq*4) = o;
}

// =================================================================================
extern "C" void kernel_launch(void* const* d_in, const int* in_sizes, int n_in,
                              void* d_out, int out_size, void* d_ws, size_t ws_size,
                              hipStream_t stream) {
  const float* l        = (const float*)d_in[0];
  const float* s        = (const float*)d_in[1];
  const float* m1_ln_w  = (const float*)d_in[2];
  const float* m1_ln_b  = (const float*)d_in[3];
  const float* m1_in_w  = (const float*)d_in[4];
  const float* m1_cw    = (const float*)d_in[5];
  const float* m1_cb    = (const float*)d_in[6];
  const float* m1_xp_w  = (const float*)d_in[7];
  const float* m1_dt_w  = (const float*)d_in[8];
  const float* m1_dt_b  = (const float*)d_in[9];
  const float* m1_Alog  = (const float*)d_in[10];
  const float* m1_D     = (const float*)d_in[11];
  const float* m1_out_w = (const float*)d_in[12];
  const float* m2_ln_w  = (const float*)d_in[13];
  const float* m2_ln_b  = (const float*)d_in[14];
  const float* m2_in_w  = (const float*)d_in[15];
  const float* m2_cw    = (const float*)d_in[16];
  const float* m2_cb    = (const float*)d_in[17];
  const float* m2_xp_w  = (const float*)d_in[18];
  const float* m2_dt_w  = (const float*)d_in[19];
  const float* m2_dt_b  = (const float*)d_in[20];
  const float* m2_Alog  = (const float*)d_in[21];
  const float* m2_D     = (const float*)d_in[22];
  const float* m2_out_w = (const float*)d_in[23];
  const float* c1_w     = (const float*)d_in[24];
  const float* c1_b     = (const float*)d_in[25];
  const float* bn1_g    = (const float*)d_in[26];
  const float* bn1_b    = (const float*)d_in[27];
  const float* c2_w     = (const float*)d_in[28];
  const float* c2_b     = (const float*)d_in[29];
  const float* bn2_g    = (const float*)d_in[30];
  const float* bn2_b    = (const float*)d_in[31];

  float* ws = (float*)d_ws;
  const size_t L = L_TOT;
  float* xc1      = ws;               // 64L
  float* z1       = ws + 64*L;        // 64L
  float* B1       = ws + 128*L;       // 16L   (reused by stage 2)
  float* C1       = ws + 144*L;       // 16L   (reused by stage 2)
  float* dtp1     = ws + 160*L;       // 2L    (reused by stage 2)
  float* conv1raw = ws + 162*L;       // 16L
  float* xc2      = ws + 178*L;       // 32L
  float* z2       = ws + 210*L;       // 32L
  float* conv2raw = ws + 242*L;       // 16L
  float* aggA     = ws + 258*L;       // 786432
  float* aggB     = aggA + 786432;
  float* carry    = aggB + 786432;    // ends at 322L
  float* stats1   = ws + 322*L;       // 32
  float* stats2   = stats1 + 32;      // 32
  unsigned short* bfin = (unsigned short*)(ws + 323*L);   // 32ch * PCH bf16
  unsigned short* wA1  = (unsigned short*)(ws + 343*L);   // 13824
  unsigned short* wA2  = wA1 + 13824;                     // 7168

  // ================= stage 1: mamba(dim=32, di=64) + conv1 + bn1(stats) ==========
  k_front<32,64,2,false,true><<<768,256,0,stream>>>(l, s, stats1, bn1_g, bn1_b,
      m1_ln_w, m1_ln_b, m1_in_w, m1_cw, m1_cb, m1_xp_w, m1_dt_w, m1_dt_b, m1_Alog,
      xc1, z1, dtp1, B1, C1, aggA, aggB,
      c1_w, wA1, c2_w, wA2, stats1, (float*)bfin);
  k_carry<768><<<64,256,0,stream>>>(aggA, aggB, carry, 1024);
  k_back<32,64,2,0><<<768,256,0,stream>>>(xc1, z1, dtp1, B1, C1,
      m1_dt_w, m1_dt_b, m1_Alog, m1_D, carry, m1_out_w, l, s,
      stats1, bn1_g, bn1_b, bfin);
  k_conv_mfma<32><<<576,256,0,stream>>>(bfin, wA1, c1_b, conv1raw, stats1);

  // ================= stage 2: mamba(dim=16, di=32) + conv2 + bn2 =================
  k_front<16,32,1,true,false><<<768,256,0,stream>>>(conv1raw, conv1raw, stats1, bn1_g, bn1_b,
      m2_ln_w, m2_ln_b, m2_in_w, m2_cw, m2_cb, m2_xp_w, m2_dt_w, m2_dt_b, m2_Alog,
      xc2, z2, dtp1, B1, C1, aggA, aggB,
      nullptr, nullptr, nullptr, nullptr, nullptr, nullptr);
  k_carry<768><<<32,256,0,stream>>>(aggA, aggB, carry, 512);
  k_back<16,32,1,1><<<768,256,0,stream>>>(xc2, z2, dtp1, B1, C1,
      m2_dt_w, m2_dt_b, m2_Alog, m2_D, carry, m2_out_w, conv1raw, conv1raw,
      stats1, bn1_g, bn1_b, bfin);
  k_conv_mfma<16><<<576,256,0,stream>>>(bfin, wA2, c2_b, conv2raw, stats2);
  k_bn_norm4<<<576,256,0,stream>>>(conv2raw, stats2, bn2_g, bn2_b, (float*)d_out);
}

// Round 14
// 265.996 us; speedup vs baseline: 1.2170x; 1.0181x over previous
//
#include <hip/hip_runtime.h>
#include <math.h>

#define L_TOT 36864
#define BN_EPS 1e-5f
#define PCH 45000   // padded channel stride: 18*50*50

typedef __attribute__((ext_vector_type(8))) short bf16x8;
typedef __attribute__((ext_vector_type(4))) float f32x4;
typedef __attribute__((ext_vector_type(4))) unsigned short u16x4;

__device__ __forceinline__ float fsigmoid(float x){ return 1.f/(1.f+__expf(-x)); }
__device__ __forceinline__ float fsoftplus(float x){
  float e = __expf(x);
  return (x>20.f)? x : __logf(1.f+e);
}
__device__ __forceinline__ unsigned short f2bf(float x){
  union { float f; unsigned u; } cv; cv.f = x;
  unsigned r = (cv.u + 0x7FFFu + ((cv.u>>16)&1u)) >> 16;
  return (unsigned short)r;
}
__device__ __forceinline__ float bf2f(unsigned short u){
  union { unsigned u32; float f; } cv; cv.u32 = ((unsigned)u)<<16; return cv.f;
}
__host__ __device__ constexpr int off3c(int r){
  return (r>=27) ? 0 : ((r/9)-1)*2500 + (((r%9)/3)-1)*50 + ((r%3)-1);
}

// =================================================================================
// k_front: fused LN (+BN-on-read) + MFMA in-proj + dwconv/SiLU + MFMA x-proj +
//          dt + pass1 chunk aggregates.  One block = one chunk of 48 timesteps.
// Intermediates xc/B/C/z spill to global as bf16 (halved traffic); dtp stays f32.
// SETUP=true (stage 1): folds conv-weight pack / bfin halo zero / stats zero.
// =================================================================================
template<int DIM, int DI, int DTR, bool DOBN, bool SETUP>
__global__ __launch_bounds__(256) void k_front(
    const float* __restrict__ x0, const float* __restrict__ x1,
    const float* __restrict__ bstats, const float* __restrict__ bg, const float* __restrict__ bbp,
    const float* __restrict__ lnw, const float* __restrict__ lnb,
    const float* __restrict__ inw,
    const float* __restrict__ cw, const float* __restrict__ cb,
    const float* __restrict__ xpw,
    const float* __restrict__ dtw, const float* __restrict__ dtb,
    const float* __restrict__ Alog,
    unsigned short* __restrict__ xcg, unsigned short* __restrict__ zg,
    float* __restrict__ dtpg, unsigned short* __restrict__ Bg, unsigned short* __restrict__ Cg,
    float* __restrict__ aggA, float* __restrict__ aggB,
    const float* __restrict__ cvw1, unsigned short* __restrict__ wA1,
    const float* __restrict__ cvw2, unsigned short* __restrict__ wA2,
    float* __restrict__ stats, float* __restrict__ bfz)
{
  constexpr int TCH  = 48;
  constexpr int ROWS = DTR + 32;
  constexpr int NSH  = 256/DI;        // threads per d-channel in scan
  constexpr int SPB  = 16/NSH;        // states per thread
  constexpr int CH   = DI*16;
  constexpr int NRT  = (2*DI)/16;     // in-proj row-tiles (8 / 4)
  constexpr int NKC  = DI/32;         // K-chunks for x-proj (K=DI: 2 / 1)
  constexpr int NRX  = 3;             // x-proj row-tiles (ceil(ROWS/16))
  constexpr int R0SZ = DI*64;         // region0: xs+halo (DI*64) / dt (DI*49)
  constexpr int O_SXC = R0SZ;         // DI*49  (aliases bf16 xn panel pre-P3)
  constexpr int O_SB  = O_SXC + DI*49;// 16*49
  constexpr int O_SC  = O_SB + 16*49; // 16*49
  constexpr int O_DTP = O_SC + 16*49; // DTR*48
  constexpr int O_WA  = O_DTP + DTR*48;     // in-proj A-frags, reused for xpw frags
  constexpr int OWASZ = ((NRT > NRX*NKC) ? NRT : NRX*NKC)*256;
  constexpr int O_XCP = O_WA + OWASZ;       // bf16 xc panel: 24*DI floats
  constexpr int SMEM  = O_XCP + 24*DI + 16;
  __shared__ float sm[SMEM];

  const int tid   = threadIdx.x;
  const int chunk = blockIdx.x;
  const int t0    = chunk*TCH;

  // ---- folded setup (stage 1): outputs consumed only by later kernels ----------
  if constexpr (SETUP){
    for (int idx = blockIdx.x*256 + tid; idx < 16*PCH; idx += 768*256)
      bfz[idx] = 0.f;                          // zero bf16 halo buffer (32-bit words)
    const int b = blockIdx.x;
    if (b < 4){
      int k = b*256 + tid;
      if (k < 864){
        int ic = k & 31, r = k >> 5;
        for (int m=0;m<16;m++){
          float v = (r < 27) ? cvw1[m*32*27 + ic*27 + r] : 0.f;
          wA1[(((k>>3)*16) + m)*8 + (k&7)] = f2bf(v);
        }
      }
    } else if (b < 6){
      int k = (b-4)*256 + tid;
      if (k < 448){
        int ic = k & 15, r = k >> 4;
        for (int m=0;m<16;m++){
          float v = (r < 27) ? cvw2[m*16*27 + ic*27 + r] : 0.f;
          wA2[(((k>>3)*16) + m)*8 + (k&7)] = f2bf(v);
        }
      }
    } else if (b == 6){
      if (tid < 64) stats[tid] = 0.f;
    }
  }

  const int i   = tid & 63;

  // ---- P012: pack inw A-frags -> LDS; x -> regs (+BN) -> LN -> bf16 B-panel ----
  {
    unsigned short* winAl = (unsigned short*)&sm[O_WA];
    unsigned short* xnl   = (unsigned short*)&sm[O_SXC];   // 64 cols x 32 k (bf16)
    for (int sidx = tid; sidx < NRT*64; sidx += 256){
      int ln  = sidx & 63;
      int row = (sidx >> 6)*16 + (ln & 15);
      int k0  = (ln >> 4)*8;
      unsigned short* wp = winAl + sidx*8;
#pragma unroll
      for (int j = 0; j < 8; j++){
        int k = k0 + j;
        wp[j] = (k < DIM) ? f2bf(inw[row*DIM + k]) : (unsigned short)0;
      }
    }
    float xn[DIM];
    const int t = t0 - 3 + i;
    const bool valid = (i < 51 && t >= 0);
#pragma unroll
    for (int c = 0; c < DIM; c++){
      float v = 0.f;
      if (valid){
        if constexpr (DOBN){
          float raw = x0[c*L_TOT + t];
          float bm = bstats[2*c]*(1.f/L_TOT);
          float bv = bstats[2*c+1]*(1.f/L_TOT) - bm*bm;
          v = (raw - bm)*rsqrtf(bv+BN_EPS)*bg[c] + bbp[c];
        } else {
          v = (c < 16) ? x0[c*L_TOT + t] : x1[(c-16)*L_TOT + t];
        }
      }
      xn[c] = v;
    }
    float s = 0.f, s2 = 0.f;
#pragma unroll
    for (int c = 0; c < DIM; c++){ s += xn[c]; s2 += xn[c]*xn[c]; }
    float m  = s*(1.f/DIM);
    float var = s2*(1.f/DIM) - m*m;
    float rs = rsqrtf(var + BN_EPS);
    unsigned short* xr = xnl + i*32;
#pragma unroll
    for (int c = 0; c < DIM; c++) xr[c] = f2bf((xn[c]-m)*rs*lnw[c] + lnb[c]);
    if constexpr (DIM < 32){
#pragma unroll
      for (int c = DIM; c < 32; c++) xr[c] = 0;
    }
  }
  __syncthreads();

  // ---- P2-MFMA: in-proj D = inw x xn.  wave = 16-col tile, NRT row-tiles -------
  {
    const unsigned short* winAl = (const unsigned short*)&sm[O_WA];
    const unsigned short* xnl   = (const unsigned short*)&sm[O_SXC];
    const int ln  = tid & 63;
    const int wv  = tid >> 6;              // col-tile
    const int col = wv*16 + (ln & 15);
    bf16x8 bfr = *reinterpret_cast<const bf16x8*>(xnl + (size_t)col*32 + (ln>>4)*8);
    f32x4 zero = {0.f,0.f,0.f,0.f};
#pragma unroll
    for (int rt = 0; rt < NRT; rt++){
      bf16x8 af = *reinterpret_cast<const bf16x8*>(winAl + (size_t)(rt*64 + ln)*8);
      f32x4 dd = __builtin_amdgcn_mfma_f32_16x16x32_bf16(af, bfr, zero, 0, 0, 0);
#pragma unroll
      for (int r = 0; r < 4; r++){
        int row = rt*16 + (ln>>4)*4 + r;
        if (row < DI){
          if (col < 51) sm[row*64 + col] = (t0 == 0 && col < 3) ? 0.f : dd[r];
        } else {
          if (col >= 3 && col < 51) zg[(row-DI)*L_TOT + t0 + col - 3] = f2bf(dd[r]);
        }
      }
    }
  }
  __syncthreads();

  // ---- P3: dwconv (kw=4) + SiLU -> SXC f32 + bf16 xc panel; pack xpw A-frags ---
  {
    unsigned short* xcp = (unsigned short*)&sm[O_XCP];
    for (int idx = tid; idx < DI*48; idx += 256){
      int d = idx / 48, j = idx - d*48;
      const float* xr = &sm[d*64 + j];     // xr[k] = xs[t-3+k]
      float acc = cb[d] + cw[d*4+0]*xr[0] + cw[d*4+1]*xr[1]
                        + cw[d*4+2]*xr[2] + cw[d*4+3]*xr[3];
      float v = acc * fsigmoid(acc);
      sm[O_SXC + d*49 + j] = v;
      xcp[j*DI + d] = f2bf(v);
    }
    unsigned short* wfr = (unsigned short*)&sm[O_WA];   // in-proj frags dead
    for (int sidx = tid; sidx < NRX*NKC*64; sidx += 256){
      int ln = sidx & 63;
      int fi = sidx >> 6;
      int rt = fi / NKC, kc = fi - rt*NKC;
      int row = rt*16 + (ln & 15);
      int k0  = kc*32 + (ln>>4)*8;
      unsigned short* wp = wfr + sidx*8;
#pragma unroll
      for (int j = 0; j < 8; j++)
        wp[j] = (row < ROWS) ? f2bf(xpw[row*DI + k0 + j]) : (unsigned short)0;
    }
  }
  __syncthreads();

  // ---- P4-MFMA: x-proj D = xpw x xc -> dtp | B | C
  {
    const unsigned short* wfr = (const unsigned short*)&sm[O_WA];
    const unsigned short* xcp = (const unsigned short*)&sm[O_XCP];
    const int ln = tid & 63;
    const int wv = tid >> 6;
    for (int job = wv; job < NRX*3; job += 4){
      int rt = job / 3, ct = job - rt*3;
      int col = ct*16 + (ln & 15);
      f32x4 acc = {0.f,0.f,0.f,0.f};
#pragma unroll
      for (int kc = 0; kc < NKC; kc++){
        bf16x8 af  = *reinterpret_cast<const bf16x8*>(wfr + (size_t)((rt*NKC+kc)*64 + ln)*8);
        bf16x8 bfr = *reinterpret_cast<const bf16x8*>(xcp + (size_t)col*DI + kc*32 + (ln>>4)*8);
        acc = __builtin_amdgcn_mfma_f32_16x16x32_bf16(af, bfr, acc, 0, 0, 0);
      }
#pragma unroll
      for (int r = 0; r < 4; r++){
        int row = rt*16 + (ln>>4)*4 + r;
        if (row < DTR)           sm[O_DTP + row*48 + col] = acc[r];
        else if (row < DTR+16)   sm[O_SB + (row-DTR)*49 + col] = acc[r];
        else if (row < ROWS)     sm[O_SC + (row-DTR-16)*49 + col] = acc[r];
      }
    }
  }
  __syncthreads();

  // ---- P5: dt = softplus(dtb + dtw*dtp) -> region0 (xs dead)
  for (int idx = tid; idx < DI*48; idx += 256){
    int d = idx / 48, j = idx - d*48;
    float pre = dtb[d] + dtw[d*DTR]*sm[O_DTP + j];
    if (DTR > 1) pre += dtw[d*DTR + DTR-1]*sm[O_DTP + (DTR-1)*48 + j];
    sm[d*49 + j] = fsoftplus(pre);
  }
  __syncthreads();

  // ---- P6: spill xc/B/C (bf16) + dtp (f32) to global (stores fly during pass1)
  for (int idx = tid; idx < DI*12; idx += 256){
    int d = idx / 12, q = idx - d*12;
    u16x4 v;
    v[0] = f2bf(sm[O_SXC + d*49 + q*4+0]);
    v[1] = f2bf(sm[O_SXC + d*49 + q*4+1]);
    v[2] = f2bf(sm[O_SXC + d*49 + q*4+2]);
    v[3] = f2bf(sm[O_SXC + d*49 + q*4+3]);
    *reinterpret_cast<u16x4*>(xcg + d*L_TOT + t0 + q*4) = v;
  }
  for (int idx = tid; idx < DTR*12; idx += 256){
    int r = idx / 12, q = idx - r*12;
    *reinterpret_cast<float4*>(dtpg + r*L_TOT + t0 + q*4) =
      make_float4(sm[O_DTP + r*48 + q*4+0], sm[O_DTP + r*48 + q*4+1],
                  sm[O_DTP + r*48 + q*4+2], sm[O_DTP + r*48 + q*4+3]);
  }
  for (int idx = tid; idx < 32*12; idx += 256){
    int r = idx / 12, q = idx - r*12;
    const float* src = (r < 16) ? &sm[O_SB + r*49 + q*4] : &sm[O_SC + (r-16)*49 + q*4];
    unsigned short* dst = (r < 16) ? (Bg + r*L_TOT + t0 + q*4)
                                   : (Cg + (r-16)*L_TOT + t0 + q*4);
    u16x4 v;
    v[0]=f2bf(src[0]); v[1]=f2bf(src[1]); v[2]=f2bf(src[2]); v[3]=f2bf(src[3]);
    *reinterpret_cast<u16x4*>(dst) = v;
  }

  // ---- P7: pass1 scan -> per-chunk (A,B) aggregates
  {
    const int d  = tid / NSH;
    const int sh = tid - d*NSH;
    float Av[SPB], Ar[SPB], Br[SPB];
#pragma unroll
    for (int j = 0; j < SPB; j++){
      Av[j] = -__expf(Alog[d*16 + sh*SPB + j]);
      Ar[j] = 1.f; Br[j] = 0.f;
    }
    for (int t = 0; t < TCH; t++){
      float dtv = sm[d*49 + t];
      float bb2 = dtv * sm[O_SXC + d*49 + t];
#pragma unroll
      for (int j = 0; j < SPB; j++){
        float a2 = __expf(dtv*Av[j]);
        Ar[j] *= a2;
        Br[j] = a2*Br[j] + bb2*sm[O_SB + (sh*SPB+j)*49 + t];
      }
    }
    const int o = chunk*CH + tid*SPB;
    if constexpr (SPB == 4){
      *reinterpret_cast<float4*>(&aggA[o]) = make_float4(Ar[0],Ar[1],Ar[2],Ar[3]);
      *reinterpret_cast<float4*>(&aggB[o]) = make_float4(Br[0],Br[1],Br[2],Br[3]);
    } else {
      *reinterpret_cast<float2*>(&aggA[o]) = make_float2(Ar[0],Ar[1]);
      *reinterpret_cast<float2*>(&aggB[o]) = make_float2(Br[0],Br[1]);
    }
  }
}

// ---------------- parallel scan over chunk aggregates -> carries ------------------
// 16 channels x 16 segments per 256-thread block; grid = CH/16 blocks.
template<int NCH>
__global__ __launch_bounds__(256) void k_carry(const float* __restrict__ aggA,
                        const float* __restrict__ aggB,
                        float* __restrict__ carry, int CH) {
  constexpr int SEG = NCH/16;         // 48 chunks per segment
  const int chl = threadIdx.x & 15;
  const int seg = threadIdx.x >> 4;
  const int ch  = blockIdx.x*16 + chl;
  const int c0  = seg*SEG;
  float a = 1.f, b = 0.f;
  for (int cb=c0; cb<c0+SEG; cb+=8){
    float av[8], bv[8];
#pragma unroll
    for (int k=0;k<8;k++){ av[k]=aggA[(cb+k)*CH+ch]; bv[k]=aggB[(cb+k)*CH+ch]; }
#pragma unroll
    for (int k=0;k<8;k++){ a = a*av[k]; b = av[k]*b + bv[k]; }
  }
  __shared__ float sa[16][17], sb[16][17];
  sa[seg][chl]=a; sb[seg][chl]=b;
  __syncthreads();
  if (threadIdx.x < 16){
    float pa=1.f, pb=0.f;
    for (int g=0; g<16; g++){
      float ca=sa[g][threadIdx.x], cb2=sb[g][threadIdx.x];
      sa[g][threadIdx.x]=pa; sb[g][threadIdx.x]=pb;
      float na = pa*ca;
      float nb = ca*pb + cb2;
      pa=na; pb=nb;
    }
  }
  __syncthreads();
  float h = sb[seg][chl];
  for (int cb=c0; cb<c0+SEG; cb+=8){
    float av[8], bv[8];
#pragma unroll
    for (int k=0;k<8;k++){ av[k]=aggA[(cb+k)*CH+ch]; bv[k]=aggB[(cb+k)*CH+ch]; }
#pragma unroll
    for (int k=0;k<8;k++){ carry[(cb+k)*CH+ch]=h; h = av[k]*h + bv[k]; }
  }
}

// =================================================================================
// k_back: fused pass2 scan + z-gate + MFMA out-proj + residual -> bf16 padded.
// xc/B/C/z arrive as bf16 (converted on LDS load); dt recomputed from f32 dtp.
// =================================================================================
template<int DIM, int DI, int DTR, int RES>
__global__ __launch_bounds__(256) void k_back(
    const unsigned short* __restrict__ xcg, const unsigned short* __restrict__ zg,
    const float* __restrict__ dtpg, const unsigned short* __restrict__ Bg,
    const unsigned short* __restrict__ Cg,
    const float* __restrict__ dtw, const float* __restrict__ dtb,
    const float* __restrict__ Alog, const float* __restrict__ Dp,
    const float* __restrict__ carry,
    const float* __restrict__ ow,
    const float* __restrict__ r0src, const float* __restrict__ r1src,
    const float* __restrict__ bstats, const float* __restrict__ bg, const float* __restrict__ bbp,
    unsigned short* __restrict__ rp)
{
  constexpr int TCH = 48;
  constexpr int NSH = 256/DI;
  constexpr int SPB = 16/NSH;
  constexpr int NRO = DIM/16;            // out-proj row-tiles (2 / 1)
  constexpr int NKC = DI/32;             // K-chunks (2 / 1)
  constexpr int O_SXC = 0;               // DI*49  (later: ow A-frags)
  constexpr int O_SDT = O_SXC + DI*49;   // DI*49  (later: bf16 y panel)
  constexpr int O_SB  = O_SDT + DI*49;   // 16*49
  constexpr int O_SC  = O_SB + 16*49;    // 16*49
  constexpr int O_SY  = O_SC + 16*49;    // DI*49
  constexpr int O_DTP = O_SY + DI*49;    // DTR*48
  constexpr int SMEM  = O_DTP + DTR*48 + 64;
  __shared__ float sm[SMEM];
  const int tid   = threadIdx.x;
  const int chunk = blockIdx.x;
  const int t0    = chunk*TCH;

  // ---- load xc / B / C (bf16->f32) and dtp (f32) into LDS
  for (int idx = tid; idx < DI*12; idx += 256){
    int d = idx / 12, q = idx - d*12;
    u16x4 v = *reinterpret_cast<const u16x4*>(xcg + d*L_TOT + t0 + q*4);
    sm[O_SXC + d*49 + q*4+0] = bf2f(v[0]); sm[O_SXC + d*49 + q*4+1] = bf2f(v[1]);
    sm[O_SXC + d*49 + q*4+2] = bf2f(v[2]); sm[O_SXC + d*49 + q*4+3] = bf2f(v[3]);
  }
  for (int idx = tid; idx < DTR*12; idx += 256){
    int r = idx / 12, q = idx - r*12;
    float4 v = *reinterpret_cast<const float4*>(dtpg + r*L_TOT + t0 + q*4);
    sm[O_DTP + r*48 + q*4+0] = v.x; sm[O_DTP + r*48 + q*4+1] = v.y;
    sm[O_DTP + r*48 + q*4+2] = v.z; sm[O_DTP + r*48 + q*4+3] = v.w;
  }
  for (int idx = tid; idx < 32*12; idx += 256){
    int r = idx / 12, q = idx - r*12;
    const unsigned short* src = (r < 16) ? (Bg + r*L_TOT + t0 + q*4)
                                         : (Cg + (r-16)*L_TOT + t0 + q*4);
    float* dst = (r < 16) ? &sm[O_SB + r*49 + q*4] : &sm[O_SC + (r-16)*49 + q*4];
    u16x4 v = *reinterpret_cast<const u16x4*>(src);
    dst[0]=bf2f(v[0]); dst[1]=bf2f(v[1]); dst[2]=bf2f(v[2]); dst[3]=bf2f(v[3]);
  }
  __syncthreads();
  // ---- dt = softplus(dtb + dtw*dtp)
  for (int idx = tid; idx < DI*48; idx += 256){
    int d = idx / 48, j = idx - d*48;
    float pre = dtb[d] + dtw[d*DTR]*sm[O_DTP + j];
    if (DTR > 1) pre += dtw[d*DTR + DTR-1]*sm[O_DTP + 48 + j];
    sm[O_SDT + d*49 + j] = fsoftplus(pre);
  }
  __syncthreads();

  // ---- pass2 scan: h update + y = sum_s h*C + xc*D -> SY
  {
    const int d  = tid / NSH;
    const int sh = tid - d*NSH;
    float Av[SPB], h[SPB];
#pragma unroll
    for (int j = 0; j < SPB; j++){
      Av[j] = -__expf(Alog[d*16 + sh*SPB + j]);
      h[j]  = carry[chunk*(DI*16) + tid*SPB + j];
    }
    const float Dv = Dp[d];
    for (int t = 0; t < TCH; t++){
      float dtv = sm[O_SDT + d*49 + t];
      float xcv = sm[O_SXC + d*49 + t];
      float bb2 = dtv*xcv;
      float p = 0.f;
#pragma unroll
      for (int j = 0; j < SPB; j++){
        float a2 = __expf(dtv*Av[j]);
        h[j] = a2*h[j] + bb2*sm[O_SB + (sh*SPB+j)*49 + t];
        p += h[j]*sm[O_SC + (sh*SPB+j)*49 + t];
      }
#pragma unroll
      for (int o = 1; o < NSH; o <<= 1) p += __shfl_xor(p, o);
      if (sh == 0) sm[O_SY + d*49 + t] = p + xcv*Dv;
    }
  }
  __syncthreads();

  // ---- gate -> bf16 y panel (over dead dt); pack ow A-frags (over dead xc) -----
  {
    unsigned short* yp  = (unsigned short*)&sm[O_SDT];
    unsigned short* wfr = (unsigned short*)&sm[O_SXC];
    for (int sidx = tid; sidx < NRO*NKC*64; sidx += 256){
      int ln = sidx & 63;
      int fi = sidx >> 6;
      int rt = fi / NKC, kc = fi - rt*NKC;
      int row = rt*16 + (ln & 15);
      int k0  = kc*32 + (ln>>4)*8;
      unsigned short* wp = wfr + sidx*8;
#pragma unroll
      for (int j = 0; j < 8; j++) wp[j] = f2bf(ow[row*DI + k0 + j]);
    }
    for (int idx = tid; idx < DI*12; idx += 256){
      int d = idx / 12, q = idx - d*12;
      u16x4 zv4 = *reinterpret_cast<const u16x4*>(zg + d*L_TOT + t0 + q*4);
      float z0 = bf2f(zv4[0]), z1 = bf2f(zv4[1]), z2 = bf2f(zv4[2]), z3 = bf2f(zv4[3]);
      yp[(q*4+0)*DI + d] = f2bf(sm[O_SY + d*49 + q*4+0] * z0*fsigmoid(z0));
      yp[(q*4+1)*DI + d] = f2bf(sm[O_SY + d*49 + q*4+1] * z1*fsigmoid(z1));
      yp[(q*4+2)*DI + d] = f2bf(sm[O_SY + d*49 + q*4+2] * z2*fsigmoid(z2));
      yp[(q*4+3)*DI + d] = f2bf(sm[O_SY + d*49 + q*4+3] * z3*fsigmoid(z3));
    }
  }
  __syncthreads();

  // ---- out-proj via MFMA + residual -> padded bf16 conv input ------------------
  {
    const unsigned short* yp  = (const unsigned short*)&sm[O_SDT];
    const unsigned short* wfr = (const unsigned short*)&sm[O_SXC];
    const int ln = tid & 63;
    const int wv = tid >> 6;
    const int zz = chunk / 48, yy = chunk - zz*48;     // 48 cols = one (zz,yy) row
    for (int job = wv; job < NRO*3; job += 4){
      int rt = job / 3, ct = job - rt*3;
      int col = ct*16 + (ln & 15);
      f32x4 acc = {0.f,0.f,0.f,0.f};
#pragma unroll
      for (int kc = 0; kc < NKC; kc++){
        bf16x8 af  = *reinterpret_cast<const bf16x8*>(wfr + (size_t)((rt*NKC+kc)*64 + ln)*8);
        bf16x8 bfr = *reinterpret_cast<const bf16x8*>(yp + (size_t)col*DI + kc*32 + (ln>>4)*8);
        acc = __builtin_amdgcn_mfma_f32_16x16x32_bf16(af, bfr, acc, 0, 0, 0);
      }
      const int t  = t0 + col;
      const int pb = (zz+1)*2500 + (yy+1)*50 + (col+1);
#pragma unroll
      for (int r = 0; r < 4; r++){
        int row = rt*16 + (ln>>4)*4 + r;
        float res;
        if (RES == 0){
          res = (row < 16) ? r0src[row*L_TOT + t] : r1src[(row-16)*L_TOT + t];
        } else {
          float bm = bstats[2*row]*(1.f/L_TOT);
          float bv = bstats[2*row+1]*(1.f/L_TOT) - bm*bm;
          res = (r0src[row*L_TOT + t] - bm)*rsqrtf(bv+BN_EPS)*bg[row] + bbp[row];
        }
        rp[row*PCH + pb] = f2bf(acc[r] + res);
      }
    }
  }
}

// ---------------- conv3d via MFMA implicit GEMM + fused BN partial sums -----------
template<int IC>
__global__ __launch_bounds__(256) void k_conv_mfma(const unsigned short* __restrict__ bin,
                         const unsigned short* __restrict__ wA,
                         const float* __restrict__ bias, float* __restrict__ out,
                         float* __restrict__ stats) {
  constexpr int NKB = (IC==32) ? 27 : 14;
  __shared__ float sred[32];
  if (threadIdx.x < 32) sred[threadIdx.x] = 0.f;
  __syncthreads();
  const int lane = threadIdx.x & 63;
  const int n = lane & 15, quad = lane >> 4;
  const int tile = blockIdx.x*4 + (threadIdx.x >> 6);
  const int t = tile*16 + n;
  int zz = t / 2304;
  int r2 = t - zz*2304;
  int yy = r2 / 48;
  int xx = r2 - yy*48;
  int pb = (zz+1)*2500 + (yy+1)*50 + (xx+1);
  const unsigned short* bp[8];
#pragma unroll
  for (int j=0;j<8;j++){
    int e = quad*8 + j;
    int ic = (IC==32) ? e : (e & 15);
    bp[j] = bin + ic*PCH + pb;
  }
  const int rq = (IC==32) ? 0 : (quad >> 1);
  f32x4 acc = {0.f, 0.f, 0.f, 0.f};
#pragma unroll
  for (int kb=0; kb<NKB; kb++){
    bf16x8 af = *reinterpret_cast<const bf16x8*>(wA + (size_t)((kb*4+quad)*16 + n)*8);
    int off;
    if (IC==32) off = off3c(kb);
    else        off = rq ? off3c(2*kb+1) : off3c(2*kb);
    bf16x8 bf;
#pragma unroll
    for (int j=0;j<8;j++) bf[j] = (short)bp[j][off];
    acc = __builtin_amdgcn_mfma_f32_16x16x32_bf16(af, bf, acc, 0, 0, 0);
  }
  float vs[4];
#pragma unroll
  for (int reg=0; reg<4; reg++){
    int m = quad*4 + reg;
    float v = acc[reg] + bias[m];
    out[m*L_TOT + t] = v;
    vs[reg] = v;
  }
#pragma unroll
  for (int reg=0; reg<4; reg++){
    float a = vs[reg], b2 = vs[reg]*vs[reg];
#pragma unroll
    for (int o=1; o<16; o<<=1){ a += __shfl_xor(a,o); b2 += __shfl_xor(b2,o); }
    if (n == 0){
      atomicAdd(&sred[quad*4+reg], a);
      atomicAdd(&sred[16 + quad*4+reg], b2);
    }
  }
  __syncthreads();
  if (threadIdx.x < 16){
    atomicAdd(&stats[2*threadIdx.x],   sred[threadIdx.x]);
    atomicAdd(&stats[2*threadIdx.x+1], sred[16+threadIdx.x]);
  }
}

// ---------------- BN normalize, float4 --------------------------------------------
__global__ void k_bn_norm4(const float* __restrict__ raw, const float* __restrict__ stats,
                           const float* __restrict__ g, const float* __restrict__ b,
                           float* __restrict__ out) {
  int i = blockIdx.x*256 + threadIdx.x;         // over 16*L_TOT/4
  int c = i / (L_TOT/4);
  int tq = i - c*(L_TOT/4);
  float m = stats[2*c]*(1.f/L_TOT);
  float v = stats[2*c+1]*(1.f/L_TOT) - m*m;
  float sc = rsqrtf(v+BN_EPS)*g[c];
  float bs = b[c] - m*sc;
  float4 x = *reinterpret_cast<const float4*>(raw + c*L_TOT + tq*4);
  float4 o = make_float4(x.x*sc+bs, x.y*sc+bs, x.z*sc+bs, x.w*sc+bs);
  *reinterpret_cast<float4*>(out + c*L_TOT + tq*4) = o;
}

// =================================================================================
extern "C" void kernel_launch(void* const* d_in, const int* in_sizes, int n_in,
                              void* d_out, int out_size, void* d_ws, size_t ws_size,
                              hipStream_t stream) {
  const float* l        = (const float*)d_in[0];
  const float* s        = (const float*)d_in[1];
  const float* m1_ln_w  = (const float*)d_in[2];
  const float* m1_ln_b  = (const float*)d_in[3];
  const float* m1_in_w  = (const float*)d_in[4];
  const float* m1_cw    = (const float*)d_in[5];
  const float* m1_cb    = (const float*)d_in[6];
  const float* m1_xp_w  = (const float*)d_in[7];
  const float* m1_dt_w  = (const float*)d_in[8];
  const float* m1_dt_b  = (const float*)d_in[9];
  const float* m1_Alog  = (const float*)d_in[10];
  const float* m1_D     = (const float*)d_in[11];
  const float* m1_out_w = (const float*)d_in[12];
  const float* m2_ln_w  = (const float*)d_in[13];
  const float* m2_ln_b  = (const float*)d_in[14];
  const float* m2_in_w  = (const float*)d_in[15];
  const float* m2_cw    = (const float*)d_in[16];
  const float* m2_cb    = (const float*)d_in[17];
  const float* m2_xp_w  = (const float*)d_in[18];
  const float* m2_dt_w  = (const float*)d_in[19];
  const float* m2_dt_b  = (const float*)d_in[20];
  const float* m2_Alog  = (const float*)d_in[21];
  const float* m2_D     = (const float*)d_in[22];
  const float* m2_out_w = (const float*)d_in[23];
  const float* c1_w     = (const float*)d_in[24];
  const float* c1_b     = (const float*)d_in[25];
  const float* bn1_g    = (const float*)d_in[26];
  const float* bn1_b    = (const float*)d_in[27];
  const float* c2_w     = (const float*)d_in[28];
  const float* c2_b     = (const float*)d_in[29];
  const float* bn2_g    = (const float*)d_in[30];
  const float* bn2_b    = (const float*)d_in[31];

  float* ws = (float*)d_ws;
  const size_t L = L_TOT;
  unsigned short* xc1b = (unsigned short*)(ws);            // 64 rows bf16 (32L f32)
  unsigned short* z1b  = (unsigned short*)(ws + 64*L);     // 64 rows bf16
  unsigned short* B1b  = (unsigned short*)(ws + 128*L);    // 16 rows bf16
  unsigned short* C1b  = (unsigned short*)(ws + 144*L);    // 16 rows bf16
  float* dtp1     = ws + 160*L;       // 2L f32 (shared both stages)
  float* conv1raw = ws + 162*L;       // 16L
  float* conv2raw = ws + 242*L;       // 16L
  float* aggA     = ws + 258*L;       // 786432
  float* aggB     = aggA + 786432;
  float* carry    = aggB + 786432;    // ends at 322L
  float* stats1   = ws + 322*L;       // 32
  float* stats2   = stats1 + 32;      // 32
  unsigned short* bfin = (unsigned short*)(ws + 323*L);   // 32ch * PCH bf16
  unsigned short* wA1  = (unsigned short*)(ws + 343*L);   // 13824
  unsigned short* wA2  = wA1 + 13824;                     // 7168

  // ================= stage 1: mamba(dim=32, di=64) + conv1 + bn1(stats) ==========
  k_front<32,64,2,false,true><<<768,256,0,stream>>>(l, s, stats1, bn1_g, bn1_b,
      m1_ln_w, m1_ln_b, m1_in_w, m1_cw, m1_cb, m1_xp_w, m1_dt_w, m1_dt_b, m1_Alog,
      xc1b, z1b, dtp1, B1b, C1b, aggA, aggB,
      c1_w, wA1, c2_w, wA2, stats1, (float*)bfin);
  k_carry<768><<<64,256,0,stream>>>(aggA, aggB, carry, 1024);
  k_back<32,64,2,0><<<768,256,0,stream>>>(xc1b, z1b, dtp1, B1b, C1b,
      m1_dt_w, m1_dt_b, m1_Alog, m1_D, carry, m1_out_w, l, s,
      stats1, bn1_g, bn1_b, bfin);
  k_conv_mfma<32><<<576,256,0,stream>>>(bfin, wA1, c1_b, conv1raw, stats1);

  // ================= stage 2: mamba(dim=16, di=32) + conv2 + bn2 =================
  k_front<16,32,1,true,false><<<768,256,0,stream>>>(conv1raw, conv1raw, stats1, bn1_g, bn1_b,
      m2_ln_w, m2_ln_b, m2_in_w, m2_cw, m2_cb, m2_xp_w, m2_dt_w, m2_dt_b, m2_Alog,
      xc1b, z1b, dtp1, B1b, C1b, aggA, aggB,
      nullptr, nullptr, nullptr, nullptr, nullptr, nullptr);
  k_carry<768><<<32,256,0,stream>>>(aggA, aggB, carry, 512);
  k_back<16,32,1,1><<<768,256,0,stream>>>(xc1b, z1b, dtp1, B1b, C1b,
      m2_dt_w, m2_dt_b, m2_Alog, m2_D, carry, m2_out_w, conv1raw, conv1raw,
      stats1, bn1_g, bn1_b, bfin);
  k_conv_mfma<16><<<576,256,0,stream>>>(bfin, wA2, c2_b, conv2raw, stats2);
  k_bn_norm4<<<576,256,0,stream>>>(conv2raw, stats2, bn2_g, bn2_b, (float*)d_out);
}

// Round 15
// 264.823 us; speedup vs baseline: 1.2224x; 1.0044x over previous
//
#include <hip/hip_runtime.h>
#include <math.h>

#define L_TOT 36864
#define BN_EPS 1e-5f
#define PCH 45000   // padded spatial stride: 18*50*50

typedef __attribute__((ext_vector_type(8))) short bf16x8;
typedef __attribute__((ext_vector_type(4))) float f32x4;
typedef __attribute__((ext_vector_type(4))) unsigned short u16x4;

__device__ __forceinline__ float fsigmoid(float x){ return 1.f/(1.f+__expf(-x)); }
__device__ __forceinline__ float fsoftplus(float x){
  float e = __expf(x);
  return (x>20.f)? x : __logf(1.f+e);
}
__device__ __forceinline__ unsigned short f2bf(float x){
  union { float f; unsigned u; } cv; cv.f = x;
  unsigned r = (cv.u + 0x7FFFu + ((cv.u>>16)&1u)) >> 16;
  return (unsigned short)r;
}
__device__ __forceinline__ float bf2f(unsigned short u){
  union { unsigned u32; float f; } cv; cv.u32 = ((unsigned)u)<<16; return cv.f;
}
__host__ __device__ constexpr int off3c(int r){
  return (r>=27) ? 0 : ((r/9)-1)*2500 + (((r%9)/3)-1)*50 + ((r%3)-1);
}

// =================================================================================
// k_front: fused LN (+BN-on-read) + MFMA in-proj + dwconv/SiLU + MFMA x-proj +
//          dt + pass1 chunk aggregates.  One block = one chunk of 48 timesteps.
// Intermediates xc/B/C/z spill to global as bf16 (halved traffic); dtp stays f32.
// SETUP=true (stage 1): folds conv-weight pack / bfin halo zero / stats zero.
// =================================================================================
template<int DIM, int DI, int DTR, bool DOBN, bool SETUP>
__global__ __launch_bounds__(256) void k_front(
    const float* __restrict__ x0, const float* __restrict__ x1,
    const float* __restrict__ bstats, const float* __restrict__ bg, const float* __restrict__ bbp,
    const float* __restrict__ lnw, const float* __restrict__ lnb,
    const float* __restrict__ inw,
    const float* __restrict__ cw, const float* __restrict__ cb,
    const float* __restrict__ xpw,
    const float* __restrict__ dtw, const float* __restrict__ dtb,
    const float* __restrict__ Alog,
    unsigned short* __restrict__ xcg, unsigned short* __restrict__ zg,
    float* __restrict__ dtpg, unsigned short* __restrict__ Bg, unsigned short* __restrict__ Cg,
    float* __restrict__ aggA, float* __restrict__ aggB,
    const float* __restrict__ cvw1, unsigned short* __restrict__ wA1,
    const float* __restrict__ cvw2, unsigned short* __restrict__ wA2,
    float* __restrict__ stats, float* __restrict__ bfz)
{
  constexpr int TCH  = 48;
  constexpr int ROWS = DTR + 32;
  constexpr int NSH  = 256/DI;        // threads per d-channel in scan
  constexpr int SPB  = 16/NSH;        // states per thread
  constexpr int CH   = DI*16;
  constexpr int NRT  = (2*DI)/16;     // in-proj row-tiles (8 / 4)
  constexpr int NKC  = DI/32;         // K-chunks for x-proj (K=DI: 2 / 1)
  constexpr int NRX  = 3;             // x-proj row-tiles (ceil(ROWS/16))
  constexpr int R0SZ = DI*64;         // region0: xs+halo (DI*64) / dt (DI*49)
  constexpr int O_SXC = R0SZ;         // DI*49  (aliases bf16 xn panel pre-P3)
  constexpr int O_SB  = O_SXC + DI*49;// 16*49
  constexpr int O_SC  = O_SB + 16*49; // 16*49
  constexpr int O_DTP = O_SC + 16*49; // DTR*48
  constexpr int O_WA  = O_DTP + DTR*48;     // in-proj A-frags, reused for xpw frags
  constexpr int OWASZ = ((NRT > NRX*NKC) ? NRT : NRX*NKC)*256;
  constexpr int O_XCP = O_WA + OWASZ;       // bf16 xc panel: 24*DI floats
  constexpr int SMEM  = O_XCP + 24*DI + 16;
  __shared__ float sm[SMEM];

  const int tid   = threadIdx.x;
  const int chunk = blockIdx.x;
  const int t0    = chunk*TCH;

  // ---- folded setup (stage 1): outputs consumed only by later kernels ----------
  if constexpr (SETUP){
    for (int idx = blockIdx.x*256 + tid; idx < 16*PCH; idx += 768*256)
      bfz[idx] = 0.f;                          // zero bf16 [spatial][32ch] buffer
    const int b = blockIdx.x;
    if (b < 4){
      int k = b*256 + tid;
      if (k < 864){
        int ic = k & 31, r = k >> 5;
        for (int m=0;m<16;m++){
          float v = (r < 27) ? cvw1[m*32*27 + ic*27 + r] : 0.f;
          wA1[(((k>>3)*16) + m)*8 + (k&7)] = f2bf(v);
        }
      }
    } else if (b < 6){
      int k = (b-4)*256 + tid;
      if (k < 448){
        int ic = k & 15, r = k >> 4;
        for (int m=0;m<16;m++){
          float v = (r < 27) ? cvw2[m*16*27 + ic*27 + r] : 0.f;
          wA2[(((k>>3)*16) + m)*8 + (k&7)] = f2bf(v);
        }
      }
    } else if (b == 6){
      if (tid < 64) stats[tid] = 0.f;
    }
  }

  const int i   = tid & 63;

  // ---- P012: pack inw A-frags -> LDS; x -> regs (+BN) -> LN -> bf16 B-panel ----
  {
    unsigned short* winAl = (unsigned short*)&sm[O_WA];
    unsigned short* xnl   = (unsigned short*)&sm[O_SXC];   // 64 cols x 32 k (bf16)
    for (int sidx = tid; sidx < NRT*64; sidx += 256){
      int ln  = sidx & 63;
      int row = (sidx >> 6)*16 + (ln & 15);
      int k0  = (ln >> 4)*8;
      unsigned short* wp = winAl + sidx*8;
#pragma unroll
      for (int j = 0; j < 8; j++){
        int k = k0 + j;
        wp[j] = (k < DIM) ? f2bf(inw[row*DIM + k]) : (unsigned short)0;
      }
    }
    float xn[DIM];
    const int t = t0 - 3 + i;
    const bool valid = (i < 51 && t >= 0);
#pragma unroll
    for (int c = 0; c < DIM; c++){
      float v = 0.f;
      if (valid){
        if constexpr (DOBN){
          float raw = x0[c*L_TOT + t];
          float bm = bstats[2*c]*(1.f/L_TOT);
          float bv = bstats[2*c+1]*(1.f/L_TOT) - bm*bm;
          v = (raw - bm)*rsqrtf(bv+BN_EPS)*bg[c] + bbp[c];
        } else {
          v = (c < 16) ? x0[c*L_TOT + t] : x1[(c-16)*L_TOT + t];
        }
      }
      xn[c] = v;
    }
    float s = 0.f, s2 = 0.f;
#pragma unroll
    for (int c = 0; c < DIM; c++){ s += xn[c]; s2 += xn[c]*xn[c]; }
    float m  = s*(1.f/DIM);
    float var = s2*(1.f/DIM) - m*m;
    float rs = rsqrtf(var + BN_EPS);
    unsigned short* xr = xnl + i*32;
#pragma unroll
    for (int c = 0; c < DIM; c++) xr[c] = f2bf((xn[c]-m)*rs*lnw[c] + lnb[c]);
    if constexpr (DIM < 32){
#pragma unroll
      for (int c = DIM; c < 32; c++) xr[c] = 0;
    }
  }
  __syncthreads();

  // ---- P2-MFMA: in-proj D = inw x xn.  wave = 16-col tile, NRT row-tiles -------
  {
    const unsigned short* winAl = (const unsigned short*)&sm[O_WA];
    const unsigned short* xnl   = (const unsigned short*)&sm[O_SXC];
    const int ln  = tid & 63;
    const int wv  = tid >> 6;              // col-tile
    const int col = wv*16 + (ln & 15);
    bf16x8 bfr = *reinterpret_cast<const bf16x8*>(xnl + (size_t)col*32 + (ln>>4)*8);
    f32x4 zero = {0.f,0.f,0.f,0.f};
#pragma unroll
    for (int rt = 0; rt < NRT; rt++){
      bf16x8 af = *reinterpret_cast<const bf16x8*>(winAl + (size_t)(rt*64 + ln)*8);
      f32x4 dd = __builtin_amdgcn_mfma_f32_16x16x32_bf16(af, bfr, zero, 0, 0, 0);
#pragma unroll
      for (int r = 0; r < 4; r++){
        int row = rt*16 + (ln>>4)*4 + r;
        if (row < DI){
          if (col < 51) sm[row*64 + col] = (t0 == 0 && col < 3) ? 0.f : dd[r];
        } else {
          if (col >= 3 && col < 51) zg[(row-DI)*L_TOT + t0 + col - 3] = f2bf(dd[r]);
        }
      }
    }
  }
  __syncthreads();

  // ---- P3: dwconv (kw=4) + SiLU -> SXC f32 + bf16 xc panel; pack xpw A-frags ---
  {
    unsigned short* xcp = (unsigned short*)&sm[O_XCP];
    for (int idx = tid; idx < DI*48; idx += 256){
      int d = idx / 48, j = idx - d*48;
      const float* xr = &sm[d*64 + j];     // xr[k] = xs[t-3+k]
      float acc = cb[d] + cw[d*4+0]*xr[0] + cw[d*4+1]*xr[1]
                        + cw[d*4+2]*xr[2] + cw[d*4+3]*xr[3];
      float v = acc * fsigmoid(acc);
      sm[O_SXC + d*49 + j] = v;
      xcp[j*DI + d] = f2bf(v);
    }
    unsigned short* wfr = (unsigned short*)&sm[O_WA];   // in-proj frags dead
    for (int sidx = tid; sidx < NRX*NKC*64; sidx += 256){
      int ln = sidx & 63;
      int fi = sidx >> 6;
      int rt = fi / NKC, kc = fi - rt*NKC;
      int row = rt*16 + (ln & 15);
      int k0  = kc*32 + (ln>>4)*8;
      unsigned short* wp = wfr + sidx*8;
#pragma unroll
      for (int j = 0; j < 8; j++)
        wp[j] = (row < ROWS) ? f2bf(xpw[row*DI + k0 + j]) : (unsigned short)0;
    }
  }
  __syncthreads();

  // ---- P4-MFMA: x-proj D = xpw x xc -> dtp | B | C
  {
    const unsigned short* wfr = (const unsigned short*)&sm[O_WA];
    const unsigned short* xcp = (const unsigned short*)&sm[O_XCP];
    const int ln = tid & 63;
    const int wv = tid >> 6;
    for (int job = wv; job < NRX*3; job += 4){
      int rt = job / 3, ct = job - rt*3;
      int col = ct*16 + (ln & 15);
      f32x4 acc = {0.f,0.f,0.f,0.f};
#pragma unroll
      for (int kc = 0; kc < NKC; kc++){
        bf16x8 af  = *reinterpret_cast<const bf16x8*>(wfr + (size_t)((rt*NKC+kc)*64 + ln)*8);
        bf16x8 bfr = *reinterpret_cast<const bf16x8*>(xcp + (size_t)col*DI + kc*32 + (ln>>4)*8);
        acc = __builtin_amdgcn_mfma_f32_16x16x32_bf16(af, bfr, acc, 0, 0, 0);
      }
#pragma unroll
      for (int r = 0; r < 4; r++){
        int row = rt*16 + (ln>>4)*4 + r;
        if (row < DTR)           sm[O_DTP + row*48 + col] = acc[r];
        else if (row < DTR+16)   sm[O_SB + (row-DTR)*49 + col] = acc[r];
        else if (row < ROWS)     sm[O_SC + (row-DTR-16)*49 + col] = acc[r];
      }
    }
  }
  __syncthreads();

  // ---- P5: dt = softplus(dtb + dtw*dtp) -> region0 (xs dead)
  for (int idx = tid; idx < DI*48; idx += 256){
    int d = idx / 48, j = idx - d*48;
    float pre = dtb[d] + dtw[d*DTR]*sm[O_DTP + j];
    if (DTR > 1) pre += dtw[d*DTR + DTR-1]*sm[O_DTP + (DTR-1)*48 + j];
    sm[d*49 + j] = fsoftplus(pre);
  }
  __syncthreads();

  // ---- P6: spill xc/B/C (bf16) + dtp (f32) to global (stores fly during pass1)
  for (int idx = tid; idx < DI*12; idx += 256){
    int d = idx / 12, q = idx - d*12;
    u16x4 v;
    v[0] = f2bf(sm[O_SXC + d*49 + q*4+0]);
    v[1] = f2bf(sm[O_SXC + d*49 + q*4+1]);
    v[2] = f2bf(sm[O_SXC + d*49 + q*4+2]);
    v[3] = f2bf(sm[O_SXC + d*49 + q*4+3]);
    *reinterpret_cast<u16x4*>(xcg + d*L_TOT + t0 + q*4) = v;
  }
  for (int idx = tid; idx < DTR*12; idx += 256){
    int r = idx / 12, q = idx - r*12;
    *reinterpret_cast<float4*>(dtpg + r*L_TOT + t0 + q*4) =
      make_float4(sm[O_DTP + r*48 + q*4+0], sm[O_DTP + r*48 + q*4+1],
                  sm[O_DTP + r*48 + q*4+2], sm[O_DTP + r*48 + q*4+3]);
  }
  for (int idx = tid; idx < 32*12; idx += 256){
    int r = idx / 12, q = idx - r*12;
    const float* src = (r < 16) ? &sm[O_SB + r*49 + q*4] : &sm[O_SC + (r-16)*49 + q*4];
    unsigned short* dst = (r < 16) ? (Bg + r*L_TOT + t0 + q*4)
                                   : (Cg + (r-16)*L_TOT + t0 + q*4);
    u16x4 v;
    v[0]=f2bf(src[0]); v[1]=f2bf(src[1]); v[2]=f2bf(src[2]); v[3]=f2bf(src[3]);
    *reinterpret_cast<u16x4*>(dst) = v;
  }

  // ---- P7: pass1 scan -> per-chunk (A,B) aggregates
  {
    const int d  = tid / NSH;
    const int sh = tid - d*NSH;
    float Av[SPB], Ar[SPB], Br[SPB];
#pragma unroll
    for (int j = 0; j < SPB; j++){
      Av[j] = -__expf(Alog[d*16 + sh*SPB + j]);
      Ar[j] = 1.f; Br[j] = 0.f;
    }
    for (int t = 0; t < TCH; t++){
      float dtv = sm[d*49 + t];
      float bb2 = dtv * sm[O_SXC + d*49 + t];
#pragma unroll
      for (int j = 0; j < SPB; j++){
        float a2 = __expf(dtv*Av[j]);
        Ar[j] *= a2;
        Br[j] = a2*Br[j] + bb2*sm[O_SB + (sh*SPB+j)*49 + t];
      }
    }
    const int o = chunk*CH + tid*SPB;
    if constexpr (SPB == 4){
      *reinterpret_cast<float4*>(&aggA[o]) = make_float4(Ar[0],Ar[1],Ar[2],Ar[3]);
      *reinterpret_cast<float4*>(&aggB[o]) = make_float4(Br[0],Br[1],Br[2],Br[3]);
    } else {
      *reinterpret_cast<float2*>(&aggA[o]) = make_float2(Ar[0],Ar[1]);
      *reinterpret_cast<float2*>(&aggB[o]) = make_float2(Br[0],Br[1]);
    }
  }
}

// ---------------- parallel scan over chunk aggregates -> carries ------------------
// 16 channels x 16 segments per 256-thread block; grid = CH/16 blocks.
template<int NCH>
__global__ __launch_bounds__(256) void k_carry(const float* __restrict__ aggA,
                        const float* __restrict__ aggB,
                        float* __restrict__ carry, int CH) {
  constexpr int SEG = NCH/16;         // 48 chunks per segment
  const int chl = threadIdx.x & 15;
  const int seg = threadIdx.x >> 4;
  const int ch  = blockIdx.x*16 + chl;
  const int c0  = seg*SEG;
  float a = 1.f, b = 0.f;
  for (int cb=c0; cb<c0+SEG; cb+=8){
    float av[8], bv[8];
#pragma unroll
    for (int k=0;k<8;k++){ av[k]=aggA[(cb+k)*CH+ch]; bv[k]=aggB[(cb+k)*CH+ch]; }
#pragma unroll
    for (int k=0;k<8;k++){ a = a*av[k]; b = av[k]*b + bv[k]; }
  }
  __shared__ float sa[16][17], sb[16][17];
  sa[seg][chl]=a; sb[seg][chl]=b;
  __syncthreads();
  if (threadIdx.x < 16){
    float pa=1.f, pb=0.f;
    for (int g=0; g<16; g++){
      float ca=sa[g][threadIdx.x], cb2=sb[g][threadIdx.x];
      sa[g][threadIdx.x]=pa; sb[g][threadIdx.x]=pb;
      float na = pa*ca;
      float nb = ca*pb + cb2;
      pa=na; pb=nb;
    }
  }
  __syncthreads();
  float h = sb[seg][chl];
  for (int cb=c0; cb<c0+SEG; cb+=8){
    float av[8], bv[8];
#pragma unroll
    for (int k=0;k<8;k++){ av[k]=aggA[(cb+k)*CH+ch]; bv[k]=aggB[(cb+k)*CH+ch]; }
#pragma unroll
    for (int k=0;k<8;k++){ carry[(cb+k)*CH+ch]=h; h = av[k]*h + bv[k]; }
  }
}

// =================================================================================
// k_back: fused pass2 scan + z-gate + MFMA out-proj + residual -> bf16 conv input
// in [spatial][32ch] layout (u16x4 per D-fragment: 4 consecutive out-channels).
// =================================================================================
template<int DIM, int DI, int DTR, int RES>
__global__ __launch_bounds__(256) void k_back(
    const unsigned short* __restrict__ xcg, const unsigned short* __restrict__ zg,
    const float* __restrict__ dtpg, const unsigned short* __restrict__ Bg,
    const unsigned short* __restrict__ Cg,
    const float* __restrict__ dtw, const float* __restrict__ dtb,
    const float* __restrict__ Alog, const float* __restrict__ Dp,
    const float* __restrict__ carry,
    const float* __restrict__ ow,
    const float* __restrict__ r0src, const float* __restrict__ r1src,
    const float* __restrict__ bstats, const float* __restrict__ bg, const float* __restrict__ bbp,
    unsigned short* __restrict__ rp)
{
  constexpr int TCH = 48;
  constexpr int NSH = 256/DI;
  constexpr int SPB = 16/NSH;
  constexpr int NRO = DIM/16;            // out-proj row-tiles (2 / 1)
  constexpr int NKC = DI/32;             // K-chunks (2 / 1)
  constexpr int O_SXC = 0;               // DI*49  (later: ow A-frags)
  constexpr int O_SDT = O_SXC + DI*49;   // DI*49  (later: bf16 y panel)
  constexpr int O_SB  = O_SDT + DI*49;   // 16*49
  constexpr int O_SC  = O_SB + 16*49;    // 16*49
  constexpr int O_SY  = O_SC + 16*49;    // DI*49
  constexpr int O_DTP = O_SY + DI*49;    // DTR*48
  constexpr int SMEM  = O_DTP + DTR*48 + 64;
  __shared__ float sm[SMEM];
  const int tid   = threadIdx.x;
  const int chunk = blockIdx.x;
  const int t0    = chunk*TCH;

  // ---- load xc / B / C (bf16->f32) and dtp (f32) into LDS
  for (int idx = tid; idx < DI*12; idx += 256){
    int d = idx / 12, q = idx - d*12;
    u16x4 v = *reinterpret_cast<const u16x4*>(xcg + d*L_TOT + t0 + q*4);
    sm[O_SXC + d*49 + q*4+0] = bf2f(v[0]); sm[O_SXC + d*49 + q*4+1] = bf2f(v[1]);
    sm[O_SXC + d*49 + q*4+2] = bf2f(v[2]); sm[O_SXC + d*49 + q*4+3] = bf2f(v[3]);
  }
  for (int idx = tid; idx < DTR*12; idx += 256){
    int r = idx / 12, q = idx - r*12;
    float4 v = *reinterpret_cast<const float4*>(dtpg + r*L_TOT + t0 + q*4);
    sm[O_DTP + r*48 + q*4+0] = v.x; sm[O_DTP + r*48 + q*4+1] = v.y;
    sm[O_DTP + r*48 + q*4+2] = v.z; sm[O_DTP + r*48 + q*4+3] = v.w;
  }
  for (int idx = tid; idx < 32*12; idx += 256){
    int r = idx / 12, q = idx - r*12;
    const unsigned short* src = (r < 16) ? (Bg + r*L_TOT + t0 + q*4)
                                         : (Cg + (r-16)*L_TOT + t0 + q*4);
    float* dst = (r < 16) ? &sm[O_SB + r*49 + q*4] : &sm[O_SC + (r-16)*49 + q*4];
    u16x4 v = *reinterpret_cast<const u16x4*>(src);
    dst[0]=bf2f(v[0]); dst[1]=bf2f(v[1]); dst[2]=bf2f(v[2]); dst[3]=bf2f(v[3]);
  }
  __syncthreads();
  // ---- dt = softplus(dtb + dtw*dtp)
  for (int idx = tid; idx < DI*48; idx += 256){
    int d = idx / 48, j = idx - d*48;
    float pre = dtb[d] + dtw[d*DTR]*sm[O_DTP + j];
    if (DTR > 1) pre += dtw[d*DTR + DTR-1]*sm[O_DTP + 48 + j];
    sm[O_SDT + d*49 + j] = fsoftplus(pre);
  }
  __syncthreads();

  // ---- pass2 scan: h update + y = sum_s h*C + xc*D -> SY
  {
    const int d  = tid / NSH;
    const int sh = tid - d*NSH;
    float Av[SPB], h[SPB];
#pragma unroll
    for (int j = 0; j < SPB; j++){
      Av[j] = -__expf(Alog[d*16 + sh*SPB + j]);
      h[j]  = carry[chunk*(DI*16) + tid*SPB + j];
    }
    const float Dv = Dp[d];
    for (int t = 0; t < TCH; t++){
      float dtv = sm[O_SDT + d*49 + t];
      float xcv = sm[O_SXC + d*49 + t];
      float bb2 = dtv*xcv;
      float p = 0.f;
#pragma unroll
      for (int j = 0; j < SPB; j++){
        float a2 = __expf(dtv*Av[j]);
        h[j] = a2*h[j] + bb2*sm[O_SB + (sh*SPB+j)*49 + t];
        p += h[j]*sm[O_SC + (sh*SPB+j)*49 + t];
      }
#pragma unroll
      for (int o = 1; o < NSH; o <<= 1) p += __shfl_xor(p, o);
      if (sh == 0) sm[O_SY + d*49 + t] = p + xcv*Dv;
    }
  }
  __syncthreads();

  // ---- gate -> bf16 y panel (over dead dt); pack ow A-frags (over dead xc) -----
  {
    unsigned short* yp  = (unsigned short*)&sm[O_SDT];
    unsigned short* wfr = (unsigned short*)&sm[O_SXC];
    for (int sidx = tid; sidx < NRO*NKC*64; sidx += 256){
      int ln = sidx & 63;
      int fi = sidx >> 6;
      int rt = fi / NKC, kc = fi - rt*NKC;
      int row = rt*16 + (ln & 15);
      int k0  = kc*32 + (ln>>4)*8;
      unsigned short* wp = wfr + sidx*8;
#pragma unroll
      for (int j = 0; j < 8; j++) wp[j] = f2bf(ow[row*DI + k0 + j]);
    }
    for (int idx = tid; idx < DI*12; idx += 256){
      int d = idx / 12, q = idx - d*12;
      u16x4 zv4 = *reinterpret_cast<const u16x4*>(zg + d*L_TOT + t0 + q*4);
      float z0 = bf2f(zv4[0]), z1 = bf2f(zv4[1]), z2 = bf2f(zv4[2]), z3 = bf2f(zv4[3]);
      yp[(q*4+0)*DI + d] = f2bf(sm[O_SY + d*49 + q*4+0] * z0*fsigmoid(z0));
      yp[(q*4+1)*DI + d] = f2bf(sm[O_SY + d*49 + q*4+1] * z1*fsigmoid(z1));
      yp[(q*4+2)*DI + d] = f2bf(sm[O_SY + d*49 + q*4+2] * z2*fsigmoid(z2));
      yp[(q*4+3)*DI + d] = f2bf(sm[O_SY + d*49 + q*4+3] * z3*fsigmoid(z3));
    }
  }
  __syncthreads();

  // ---- out-proj via MFMA + residual -> bf16 [spatial][32ch] conv input ---------
  {
    const unsigned short* yp  = (const unsigned short*)&sm[O_SDT];
    const unsigned short* wfr = (const unsigned short*)&sm[O_SXC];
    const int ln = tid & 63;
    const int wv = tid >> 6;
    const int zz = chunk / 48, yy = chunk - zz*48;     // 48 cols = one (zz,yy) row
    for (int job = wv; job < NRO*3; job += 4){
      int rt = job / 3, ct = job - rt*3;
      int col = ct*16 + (ln & 15);
      f32x4 acc = {0.f,0.f,0.f,0.f};
#pragma unroll
      for (int kc = 0; kc < NKC; kc++){
        bf16x8 af  = *reinterpret_cast<const bf16x8*>(wfr + (size_t)((rt*NKC+kc)*64 + ln)*8);
        bf16x8 bfr = *reinterpret_cast<const bf16x8*>(yp + (size_t)col*DI + kc*32 + (ln>>4)*8);
        acc = __builtin_amdgcn_mfma_f32_16x16x32_bf16(af, bfr, acc, 0, 0, 0);
      }
      const int t  = t0 + col;
      const int pb = (zz+1)*2500 + (yy+1)*50 + (col+1);
      const int row0 = rt*16 + (ln>>4)*4;
      u16x4 ov;
#pragma unroll
      for (int r = 0; r < 4; r++){
        int row = row0 + r;
        float res;
        if (RES == 0){
          res = (row < 16) ? r0src[row*L_TOT + t] : r1src[(row-16)*L_TOT + t];
        } else {
          float bm = bstats[2*row]*(1.f/L_TOT);
          float bv = bstats[2*row+1]*(1.f/L_TOT) - bm*bm;
          res = (r0src[row*L_TOT + t] - bm)*rsqrtf(bv+BN_EPS)*bg[row] + bbp[row];
        }
        ov[r] = f2bf(acc[r] + res);
      }
      *reinterpret_cast<u16x4*>(rp + (size_t)pb*32 + row0) = ov;
    }
  }
}

// ---------------- conv3d via MFMA implicit GEMM + fused BN partial sums -----------
// Input bin is [spatial][32ch] bf16: each fragment's 8 channels are one 16-B load.
template<int IC>
__global__ __launch_bounds__(256) void k_conv_mfma(const unsigned short* __restrict__ bin,
                         const unsigned short* __restrict__ wA,
                         const float* __restrict__ bias, float* __restrict__ out,
                         float* __restrict__ stats) {
  constexpr int NKB = (IC==32) ? 27 : 14;
  __shared__ float sred[32];
  if (threadIdx.x < 32) sred[threadIdx.x] = 0.f;
  __syncthreads();
  const int lane = threadIdx.x & 63;
  const int n = lane & 15, quad = lane >> 4;
  const int tile = blockIdx.x*4 + (threadIdx.x >> 6);
  const int t = tile*16 + n;
  int zz = t / 2304;
  int r2 = t - zz*2304;
  int yy = r2 / 48;
  int xx = r2 - yy*48;
  int pb = (zz+1)*2500 + (yy+1)*50 + (xx+1);
  const unsigned short* bpb = bin + (size_t)pb*32 + ((IC==32) ? quad*8 : (quad&1)*8);
  const int rq = (IC==32) ? 0 : (quad >> 1);
  f32x4 acc = {0.f, 0.f, 0.f, 0.f};
#pragma unroll
  for (int kb=0; kb<NKB; kb++){
    bf16x8 af = *reinterpret_cast<const bf16x8*>(wA + (size_t)((kb*4+quad)*16 + n)*8);
    int off;
    if (IC==32) off = off3c(kb);
    else        off = rq ? off3c(2*kb+1) : off3c(2*kb);
    bf16x8 bf = *reinterpret_cast<const bf16x8*>(bpb + (ptrdiff_t)off*32);
    acc = __builtin_amdgcn_mfma_f32_16x16x32_bf16(af, bf, acc, 0, 0, 0);
  }
  float vs[4];
#pragma unroll
  for (int reg=0; reg<4; reg++){
    int m = quad*4 + reg;
    float v = acc[reg] + bias[m];
    out[m*L_TOT + t] = v;
    vs[reg] = v;
  }
#pragma unroll
  for (int reg=0; reg<4; reg++){
    float a = vs[reg], b2 = vs[reg]*vs[reg];
#pragma unroll
    for (int o=1; o<16; o<<=1){ a += __shfl_xor(a,o); b2 += __shfl_xor(b2,o); }
    if (n == 0){
      atomicAdd(&sred[quad*4+reg], a);
      atomicAdd(&sred[16 + quad*4+reg], b2);
    }
  }
  __syncthreads();
  if (threadIdx.x < 16){
    atomicAdd(&stats[2*threadIdx.x],   sred[threadIdx.x]);
    atomicAdd(&stats[2*threadIdx.x+1], sred[16+threadIdx.x]);
  }
}

// ---------------- BN normalize, float4 --------------------------------------------
__global__ void k_bn_norm4(const float* __restrict__ raw, const float* __restrict__ stats,
                           const float* __restrict__ g, const float* __restrict__ b,
                           float* __restrict__ out) {
  int i = blockIdx.x*256 + threadIdx.x;         // over 16*L_TOT/4
  int c = i / (L_TOT/4);
  int tq = i - c*(L_TOT/4);
  float m = stats[2*c]*(1.f/L_TOT);
  float v = stats[2*c+1]*(1.f/L_TOT) - m*m;
  float sc = rsqrtf(v+BN_EPS)*g[c];
  float bs = b[c] - m*sc;
  float4 x = *reinterpret_cast<const float4*>(raw + c*L_TOT + tq*4);
  float4 o = make_float4(x.x*sc+bs, x.y*sc+bs, x.z*sc+bs, x.w*sc+bs);
  *reinterpret_cast<float4*>(out + c*L_TOT + tq*4) = o;
}

// =================================================================================
extern "C" void kernel_launch(void* const* d_in, const int* in_sizes, int n_in,
                              void* d_out, int out_size, void* d_ws, size_t ws_size,
                              hipStream_t stream) {
  const float* l        = (const float*)d_in[0];
  const float* s        = (const float*)d_in[1];
  const float* m1_ln_w  = (const float*)d_in[2];
  const float* m1_ln_b  = (const float*)d_in[3];
  const float* m1_in_w  = (const float*)d_in[4];
  const float* m1_cw    = (const float*)d_in[5];
  const float* m1_cb    = (const float*)d_in[6];
  const float* m1_xp_w  = (const float*)d_in[7];
  const float* m1_dt_w  = (const float*)d_in[8];
  const float* m1_dt_b  = (const float*)d_in[9];
  const float* m1_Alog  = (const float*)d_in[10];
  const float* m1_D     = (const float*)d_in[11];
  const float* m1_out_w = (const float*)d_in[12];
  const float* m2_ln_w  = (const float*)d_in[13];
  const float* m2_ln_b  = (const float*)d_in[14];
  const float* m2_in_w  = (const float*)d_in[15];
  const float* m2_cw    = (const float*)d_in[16];
  const float* m2_cb    = (const float*)d_in[17];
  const float* m2_xp_w  = (const float*)d_in[18];
  const float* m2_dt_w  = (const float*)d_in[19];
  const float* m2_dt_b  = (const float*)d_in[20];
  const float* m2_Alog  = (const float*)d_in[21];
  const float* m2_D     = (const float*)d_in[22];
  const float* m2_out_w = (const float*)d_in[23];
  const float* c1_w     = (const float*)d_in[24];
  const float* c1_b     = (const float*)d_in[25];
  const float* bn1_g    = (const float*)d_in[26];
  const float* bn1_b    = (const float*)d_in[27];
  const float* c2_w     = (const float*)d_in[28];
  const float* c2_b     = (const float*)d_in[29];
  const float* bn2_g    = (const float*)d_in[30];
  const float* bn2_b    = (const float*)d_in[31];

  float* ws = (float*)d_ws;
  const size_t L = L_TOT;
  unsigned short* xc1b = (unsigned short*)(ws);            // 64 rows bf16 (32L f32)
  unsigned short* z1b  = (unsigned short*)(ws + 64*L);     // 64 rows bf16
  unsigned short* B1b  = (unsigned short*)(ws + 128*L);    // 16 rows bf16
  unsigned short* C1b  = (unsigned short*)(ws + 144*L);    // 16 rows bf16
  float* dtp1     = ws + 160*L;       // 2L f32 (shared both stages)
  float* conv1raw = ws + 162*L;       // 16L
  float* conv2raw = ws + 242*L;       // 16L
  float* aggA     = ws + 258*L;       // 786432
  float* aggB     = aggA + 786432;
  float* carry    = aggB + 786432;    // ends at 322L
  float* stats1   = ws + 322*L;       // 32
  float* stats2   = stats1 + 32;      // 32
  unsigned short* bfin = (unsigned short*)(ws + 323*L);   // [PCH][32ch] bf16
  unsigned short* wA1  = (unsigned short*)(ws + 343*L);   // 13824
  unsigned short* wA2  = wA1 + 13824;                     // 7168

  // ================= stage 1: mamba(dim=32, di=64) + conv1 + bn1(stats) ==========
  k_front<32,64,2,false,true><<<768,256,0,stream>>>(l, s, stats1, bn1_g, bn1_b,
      m1_ln_w, m1_ln_b, m1_in_w, m1_cw, m1_cb, m1_xp_w, m1_dt_w, m1_dt_b, m1_Alog,
      xc1b, z1b, dtp1, B1b, C1b, aggA, aggB,
      c1_w, wA1, c2_w, wA2, stats1, (float*)bfin);
  k_carry<768><<<64,256,0,stream>>>(aggA, aggB, carry, 1024);
  k_back<32,64,2,0><<<768,256,0,stream>>>(xc1b, z1b, dtp1, B1b, C1b,
      m1_dt_w, m1_dt_b, m1_Alog, m1_D, carry, m1_out_w, l, s,
      stats1, bn1_g, bn1_b, bfin);
  k_conv_mfma<32><<<576,256,0,stream>>>(bfin, wA1, c1_b, conv1raw, stats1);

  // ================= stage 2: mamba(dim=16, di=32) + conv2 + bn2 =================
  k_front<16,32,1,true,false><<<768,256,0,stream>>>(conv1raw, conv1raw, stats1, bn1_g, bn1_b,
      m2_ln_w, m2_ln_b, m2_in_w, m2_cw, m2_cb, m2_xp_w, m2_dt_w, m2_dt_b, m2_Alog,
      xc1b, z1b, dtp1, B1b, C1b, aggA, aggB,
      nullptr, nullptr, nullptr, nullptr, nullptr, nullptr);
  k_carry<768><<<32,256,0,stream>>>(aggA, aggB, carry, 512);
  k_back<16,32,1,1><<<768,256,0,stream>>>(xc1b, z1b, dtp1, B1b, C1b,
      m2_dt_w, m2_dt_b, m2_Alog, m2_D, carry, m2_out_w, conv1raw, conv1raw,
      stats1, bn1_g, bn1_b, bfin);
  k_conv_mfma<16><<<576,256,0,stream>>>(bfin, wA2, c2_b, conv2raw, stats2);
  k_bn_norm4<<<576,256,0,stream>>>(conv2raw, stats2, bn2_g, bn2_b, (float*)d_out);
}